// Round 1
// baseline (271.319 us; speedup 1.0000x reference)
//
#include <hip/hip_runtime.h>

// ---------------------------------------------------------------------------
// CausalSelfAttention: x@Wqkv -> split heads -> causal flash attn -> @Wproj
// B=2 T=2048 C=1024 H=16 D=64. All matmuls bf16 MFMA (16x16x32), f32 accum.
// ---------------------------------------------------------------------------

typedef __attribute__((ext_vector_type(8))) __bf16 bf16x8;
typedef __attribute__((ext_vector_type(4))) float f32x4;
typedef __attribute__((ext_vector_type(8))) unsigned short u16x8;
typedef __attribute__((ext_vector_type(4))) unsigned short u16x4;

#define GAS __attribute__((address_space(1)))
#define LAS __attribute__((address_space(3)))

__device__ __forceinline__ unsigned short f2b(float f) {
  unsigned int u = __float_as_uint(f);
  unsigned int r = 0x7FFFu + ((u >> 16) & 1u);
  return (unsigned short)((u + r) >> 16);
}

// ---------------- prep kernels ----------------

__global__ void cvt_f32_to_bf16(const float* __restrict__ src,
                                unsigned short* __restrict__ dst, int n4) {
  int i = blockIdx.x * blockDim.x + threadIdx.x;
  if (i < n4) {
    float4 v = ((const float4*)src)[i];
    u16x4 o = { f2b(v.x), f2b(v.y), f2b(v.z), f2b(v.w) };
    *(u16x4*)(dst + (size_t)i * 4) = o;
  }
}

// src [K][N] f32  ->  dst [N][K] bf16
__global__ void transpose_f32_to_bf16(const float* __restrict__ src,
                                      unsigned short* __restrict__ dst,
                                      int K, int N) {
  __shared__ float tile[32][33];
  int n0 = blockIdx.x * 32, k0 = blockIdx.y * 32;
  int tx = threadIdx.x, ty = threadIdx.y;  // 32 x 8
#pragma unroll
  for (int i = 0; i < 32; i += 8)
    tile[ty + i][tx] = src[(size_t)(k0 + ty + i) * N + n0 + tx];
  __syncthreads();
#pragma unroll
  for (int i = 0; i < 32; i += 8)
    dst[(size_t)(n0 + ty + i) * K + k0 + tx] = f2b(tile[tx][ty + i]);
}

// ---------------- GEMM: C = A[M,K] * B^T[N,K]^T + bias ----------------
// m97 structure: 128x128 tile, BK=64, 4 waves, global_load_lds width 16.
// MODE 0: QKV epilogue -> scatter bf16 into Q/K/V [B,H,T,D]
// MODE 1: proj epilogue -> f32 natural [M,N]

template <int MODE>
__global__ void __launch_bounds__(256) gemm_bt(
    const unsigned short* __restrict__ A, const unsigned short* __restrict__ Bt,
    const float* __restrict__ bias,
    unsigned short* __restrict__ Oq, unsigned short* __restrict__ Ok,
    unsigned short* __restrict__ Ov, float* __restrict__ Of,
    int M, int N, int K) {
  __shared__ unsigned short As[128 * 64];
  __shared__ unsigned short Bs[128 * 64];

  const int tid = threadIdx.x;
  const int lane = tid & 63;
  const int wid = tid >> 6;
  const int wr = wid >> 1, wc = wid & 1;
  const int lr = lane & 15, lg = lane >> 4;
  const int m0 = blockIdx.x * 128;
  const int n0 = blockIdx.y * 128;

  f32x4 acc[4][4];
#pragma unroll
  for (int mi = 0; mi < 4; mi++)
#pragma unroll
    for (int ni = 0; ni < 4; ni++) acc[mi][ni] = (f32x4){0.f, 0.f, 0.f, 0.f};

  const int kt = K >> 6;
  for (int t = 0; t < kt; ++t) {
    const int k0 = t * 64;
#pragma unroll
    for (int it = 0; it < 4; ++it) {
      const int chunk_u = it * 256 + (tid & ~63);  // wave-uniform 16B-chunk base
      const int chunk = chunk_u + lane;
      const int row = chunk >> 3;
      const int col = (chunk & 7) * 8;
      __builtin_amdgcn_global_load_lds(
          (GAS unsigned int*)(A + (size_t)(m0 + row) * K + k0 + col),
          (LAS unsigned int*)(As + chunk_u * 8), 16, 0, 0);
      __builtin_amdgcn_global_load_lds(
          (GAS unsigned int*)(Bt + (size_t)(n0 + row) * K + k0 + col),
          (LAS unsigned int*)(Bs + chunk_u * 8), 16, 0, 0);
    }
    __syncthreads();  // drains vmcnt(0) then barrier

#pragma unroll
    for (int kk = 0; kk < 2; ++kk) {
      bf16x8 af[4], bfr[4];
#pragma unroll
      for (int mi = 0; mi < 4; mi++)
        af[mi] = *(const bf16x8*)(As + (wr * 64 + mi * 16 + lr) * 64 + kk * 32 + lg * 8);
#pragma unroll
      for (int ni = 0; ni < 4; ni++)
        bfr[ni] = *(const bf16x8*)(Bs + (wc * 64 + ni * 16 + lr) * 64 + kk * 32 + lg * 8);
#pragma unroll
      for (int mi = 0; mi < 4; mi++)
#pragma unroll
        for (int ni = 0; ni < 4; ni++)
          acc[mi][ni] = __builtin_amdgcn_mfma_f32_16x16x32_bf16(
              af[mi], bfr[ni], acc[mi][ni], 0, 0, 0);
    }
    __syncthreads();  // protect LDS reuse next iter
  }

  // epilogue: C/D layout col = lane&15, row = (lane>>4)*4 + r
#pragma unroll
  for (int mi = 0; mi < 4; mi++) {
#pragma unroll
    for (int ni = 0; ni < 4; ni++) {
      const int nn = n0 + wc * 64 + ni * 16 + lr;
      const float bv = bias[nn];
#pragma unroll
      for (int r = 0; r < 4; r++) {
        const int mm = m0 + wr * 64 + mi * 16 + lg * 4 + r;
        float v = acc[mi][ni][r] + bv;
        if constexpr (MODE == 0) {
          const int b = mm >> 11, tt = mm & 2047;
          const int which = nn >> 10, c = nn & 1023;
          const int h = c >> 6, d = c & 63;
          const size_t off = ((size_t)(b * 16 + h) * 2048 + tt) * 64 + d;
          unsigned short* dst = (which == 0) ? Oq : ((which == 1) ? Ok : Ov);
          dst[off] = f2b(v);
        } else {
          Of[(size_t)mm * N + nn] = v;
        }
      }
    }
  }
}

// ---------------- flash attention (causal) ----------------
// grid: B*H*(T/64) blocks of 256 threads (4 waves); each wave owns 16 q-rows.
// K tile staged via global_load_lds [64][64]; V reg-staged transposed [64][72];
// P per-wave through LDS [16][72]; online softmax in log2 domain.

__global__ void __launch_bounds__(256) attn_kernel(
    const unsigned short* __restrict__ Qh, const unsigned short* __restrict__ Kh,
    const unsigned short* __restrict__ Vh, unsigned short* __restrict__ yatt) {
  __shared__ unsigned short Ks[64 * 64];
  __shared__ unsigned short Vt[64 * 72];
  __shared__ unsigned short Pl[4 * 16 * 72];

  const int tid = threadIdx.x;
  const int lane = tid & 63;
  const int w = tid >> 6;
  const int lr = lane & 15, lg = lane >> 4;

  const int qt = blockIdx.x & 31;
  const int hh = (blockIdx.x >> 5) & 15;
  const int bb = blockIdx.x >> 9;

  const size_t head_base = ((size_t)(bb * 16 + hh)) * 2048 * 64;
  const unsigned short* Qg = Qh + head_base;
  const unsigned short* Kg = Kh + head_base;
  const unsigned short* Vg = Vh + head_base;

  const int q0w = qt * 64 + w * 16;

  bf16x8 aq[2];
  aq[0] = *(const bf16x8*)(Qg + (size_t)(q0w + lr) * 64 + lg * 8);
  aq[1] = *(const bf16x8*)(Qg + (size_t)(q0w + lr) * 64 + 32 + lg * 8);

  float m_run[4], l_run[4];
  f32x4 acc_o[4];
#pragma unroll
  for (int r = 0; r < 4; r++) { m_run[r] = -__builtin_inff(); l_run[r] = 0.f; }
#pragma unroll
  for (int dj = 0; dj < 4; dj++) acc_o[dj] = (f32x4){0.f, 0.f, 0.f, 0.f};

  const float SCL = 0.125f * 1.44269504088896340736f;  // 1/sqrt(64) * log2(e)
  const int ntiles = qt + 1;

  for (int j = 0; j < ntiles; ++j) {
    const int kv0 = j * 64;
    // stage K: 2 global_load_lds per wave (8 rows each)
#pragma unroll
    for (int it = 0; it < 2; ++it) {
      const int r0 = it * 32 + w * 8;
      const int row = r0 + (lane >> 3);
      const int col = (lane & 7) * 8;
      __builtin_amdgcn_global_load_lds(
          (GAS unsigned int*)(Kg + (size_t)(kv0 + row) * 64 + col),
          (LAS unsigned int*)(Ks + r0 * 64), 16, 0, 0);
    }
    // stage V transposed (reg-staged; pad 72 breaks bank conflicts)
#pragma unroll
    for (int rep = 0; rep < 2; ++rep) {
      const int t = rep * 32 + (tid >> 3);
      const int d0 = (tid & 7) * 8;
      u16x8 v = *(const u16x8*)(Vg + (size_t)(kv0 + t) * 64 + d0);
#pragma unroll
      for (int jj = 0; jj < 8; jj++) Vt[(d0 + jj) * 72 + t] = v[jj];
    }
    __syncthreads();

    // QK^T: S[16 q rows][64 keys]
    f32x4 s[4];
#pragma unroll
    for (int nj = 0; nj < 4; nj++) {
      bf16x8 kb0 = *(const bf16x8*)(Ks + (nj * 16 + lr) * 64 + lg * 8);
      bf16x8 kb1 = *(const bf16x8*)(Ks + (nj * 16 + lr) * 64 + 32 + lg * 8);
      f32x4 z = (f32x4){0.f, 0.f, 0.f, 0.f};
      z = __builtin_amdgcn_mfma_f32_16x16x32_bf16(aq[0], kb0, z, 0, 0, 0);
      z = __builtin_amdgcn_mfma_f32_16x16x32_bf16(aq[1], kb1, z, 0, 0, 0);
      s[nj] = z;
    }

    // causal mask + wave-parallel online softmax (log2 domain)
    float sv[4][4], pm[4];
#pragma unroll
    for (int r = 0; r < 4; r++) pm[r] = -__builtin_inff();
#pragma unroll
    for (int nj = 0; nj < 4; nj++) {
      const int key = kv0 + nj * 16 + lr;
#pragma unroll
      for (int r = 0; r < 4; r++) {
        const int qrow = q0w + lg * 4 + r;
        float v = s[nj][r] * SCL;
        v = (key <= qrow) ? v : -__builtin_inff();
        sv[nj][r] = v;
        pm[r] = fmaxf(pm[r], v);
      }
    }
#pragma unroll
    for (int r = 0; r < 4; r++) {
#pragma unroll
      for (int off = 1; off < 16; off <<= 1)
        pm[r] = fmaxf(pm[r], __shfl_xor(pm[r], off));
    }
    float scale[4], rs[4];
#pragma unroll
    for (int r = 0; r < 4; r++) {
      const float mn = fmaxf(m_run[r], pm[r]);
      scale[r] = exp2f(m_run[r] - mn);  // 0 on first tile (m_run=-inf)
      m_run[r] = mn;
      rs[r] = 0.f;
    }
    unsigned short* Pw = Pl + w * 16 * 72;
#pragma unroll
    for (int nj = 0; nj < 4; nj++) {
#pragma unroll
      for (int r = 0; r < 4; r++) {
        const float p = exp2f(sv[nj][r] - m_run[r]);  // masked -> exp2(-inf)=0
        rs[r] += p;
        Pw[(lg * 4 + r) * 72 + nj * 16 + lr] = f2b(p);
      }
    }
#pragma unroll
    for (int r = 0; r < 4; r++) {
#pragma unroll
      for (int off = 1; off < 16; off <<= 1) rs[r] += __shfl_xor(rs[r], off);
      l_run[r] = l_run[r] * scale[r] + rs[r];
#pragma unroll
      for (int dj = 0; dj < 4; dj++) acc_o[dj][r] *= scale[r];
    }

    // PV: O += P[16,64] * V[64,64]
    bf16x8 pa0 = *(const bf16x8*)(Pw + lr * 72 + lg * 8);
    bf16x8 pa1 = *(const bf16x8*)(Pw + lr * 72 + 32 + lg * 8);
#pragma unroll
    for (int dj = 0; dj < 4; dj++) {
      bf16x8 vb0 = *(const bf16x8*)(Vt + (dj * 16 + lr) * 72 + lg * 8);
      bf16x8 vb1 = *(const bf16x8*)(Vt + (dj * 16 + lr) * 72 + 32 + lg * 8);
      acc_o[dj] = __builtin_amdgcn_mfma_f32_16x16x32_bf16(pa0, vb0, acc_o[dj], 0, 0, 0);
      acc_o[dj] = __builtin_amdgcn_mfma_f32_16x16x32_bf16(pa1, vb1, acc_o[dj], 0, 0, 0);
    }
    __syncthreads();  // protect Ks/Vt before next tile's staging
  }

  // epilogue: normalize, write bf16 [B,T,C] (heads re-merged)
#pragma unroll
  for (int r = 0; r < 4; r++) {
    const float inv = 1.0f / l_run[r];
    const int t = q0w + lg * 4 + r;
    const size_t rowbase = ((size_t)(bb * 2048 + t)) * 1024 + hh * 64;
#pragma unroll
    for (int dj = 0; dj < 4; dj++)
      yatt[rowbase + dj * 16 + lr] = f2b(acc_o[dj][r] * inv);
  }
}

// ---------------- launcher ----------------

extern "C" void kernel_launch(void* const* d_in, const int* in_sizes, int n_in,
                              void* d_out, int out_size, void* d_ws,
                              size_t ws_size, hipStream_t stream) {
  (void)in_sizes; (void)n_in; (void)out_size; (void)ws_size;
  const float* x      = (const float*)d_in[0];  // [2,2048,1024]
  const float* w_qkv  = (const float*)d_in[1];  // [1024,3072]
  const float* b_qkv  = (const float*)d_in[2];  // [3072]
  const float* w_proj = (const float*)d_in[3];  // [1024,1024]
  const float* b_proj = (const float*)d_in[4];  // [1024]
  float* out = (float*)d_out;                   // [2,2048,1024] f32

  unsigned short* ws     = (unsigned short*)d_ws;
  unsigned short* xb     = ws;                                  // 4096*1024
  unsigned short* wqkvT  = xb     + (size_t)4096 * 1024;        // 3072*1024
  unsigned short* wprojT = wqkvT  + (size_t)3072 * 1024;        // 1024*1024
  unsigned short* Qh     = wprojT + (size_t)1024 * 1024;        // 2*16*2048*64
  unsigned short* Kh     = Qh     + (size_t)2 * 16 * 2048 * 64;
  unsigned short* Vh     = Kh     + (size_t)2 * 16 * 2048 * 64;
  unsigned short* yatt   = Vh     + (size_t)2 * 16 * 2048 * 64; // 4096*1024

  cvt_f32_to_bf16<<<4096, 256, 0, stream>>>(x, xb, 1048576);
  transpose_f32_to_bf16<<<dim3(96, 32), dim3(32, 8), 0, stream>>>(w_qkv, wqkvT, 1024, 3072);
  transpose_f32_to_bf16<<<dim3(32, 32), dim3(32, 8), 0, stream>>>(w_proj, wprojT, 1024, 1024);

  gemm_bt<0><<<dim3(32, 24), 256, 0, stream>>>(xb, wqkvT, b_qkv, Qh, Kh, Vh,
                                               nullptr, 4096, 3072, 1024);
  attn_kernel<<<1024, 256, 0, stream>>>(Qh, Kh, Vh, yatt);
  gemm_bt<1><<<dim3(32, 8), 256, 0, stream>>>(yatt, wprojT, b_proj, nullptr,
                                              nullptr, nullptr, out, 4096, 1024, 1024);
}

// Round 2
// 182.639 us; speedup vs baseline: 1.4855x; 1.4855x over previous
//
#include <hip/hip_runtime.h>

// ---------------------------------------------------------------------------
// CausalSelfAttention: x@Wqkv -> split heads -> causal flash attn -> @Wproj
// B=2 T=2048 C=1024 H=16 D=64. All matmuls bf16 MFMA (16x16x32), f32 accum.
// Round 2: attn rework — V pre-transposed by GEMM epilogue ([B,H,D,T]),
// K/V tiles XOR-swizzled (T2, both-sides), paired q-tiles for load balance,
// double-buffered K/V staging (one barrier per tile).
// ---------------------------------------------------------------------------

typedef __attribute__((ext_vector_type(8))) __bf16 bf16x8;
typedef __attribute__((ext_vector_type(4))) float f32x4;
typedef __attribute__((ext_vector_type(8))) unsigned short u16x8;
typedef __attribute__((ext_vector_type(4))) unsigned short u16x4;

#define GAS __attribute__((address_space(1)))
#define LAS __attribute__((address_space(3)))

__device__ __forceinline__ unsigned short f2b(float f) {
  unsigned int u = __float_as_uint(f);
  unsigned int r = 0x7FFFu + ((u >> 16) & 1u);
  return (unsigned short)((u + r) >> 16);
}

// ---------------- prep kernels ----------------

__global__ void cvt_f32_to_bf16(const float* __restrict__ src,
                                unsigned short* __restrict__ dst, int n4) {
  int i = blockIdx.x * blockDim.x + threadIdx.x;
  if (i < n4) {
    float4 v = ((const float4*)src)[i];
    u16x4 o = { f2b(v.x), f2b(v.y), f2b(v.z), f2b(v.w) };
    *(u16x4*)(dst + (size_t)i * 4) = o;
  }
}

// src [K][N] f32  ->  dst [N][K] bf16
__global__ void transpose_f32_to_bf16(const float* __restrict__ src,
                                      unsigned short* __restrict__ dst,
                                      int K, int N) {
  __shared__ float tile[32][33];
  int n0 = blockIdx.x * 32, k0 = blockIdx.y * 32;
  int tx = threadIdx.x, ty = threadIdx.y;  // 32 x 8
#pragma unroll
  for (int i = 0; i < 32; i += 8)
    tile[ty + i][tx] = src[(size_t)(k0 + ty + i) * N + n0 + tx];
  __syncthreads();
#pragma unroll
  for (int i = 0; i < 32; i += 8)
    dst[(size_t)(n0 + ty + i) * K + k0 + tx] = f2b(tile[tx][ty + i]);
}

// ---------------- GEMM: C = A[M,K] * B^T[N,K]^T + bias ----------------
// m97 structure: 128x128 tile, BK=64, 4 waves, global_load_lds width 16.
// MODE 0: QKV epilogue -> Q,K as [B,H,T,D] bf16; V as [B,H,D,T] bf16 (transposed)
// MODE 1: proj epilogue -> f32 natural [M,N]

template <int MODE>
__global__ void __launch_bounds__(256) gemm_bt(
    const unsigned short* __restrict__ A, const unsigned short* __restrict__ Bt,
    const float* __restrict__ bias,
    unsigned short* __restrict__ Oq, unsigned short* __restrict__ Ok,
    unsigned short* __restrict__ Ov, float* __restrict__ Of,
    int M, int N, int K) {
  __shared__ unsigned short As[128 * 64];
  __shared__ unsigned short Bs[128 * 64];

  const int tid = threadIdx.x;
  const int lane = tid & 63;
  const int wid = tid >> 6;
  const int wr = wid >> 1, wc = wid & 1;
  const int lr = lane & 15, lg = lane >> 4;
  const int m0 = blockIdx.x * 128;
  const int n0 = blockIdx.y * 128;

  f32x4 acc[4][4];
#pragma unroll
  for (int mi = 0; mi < 4; mi++)
#pragma unroll
    for (int ni = 0; ni < 4; ni++) acc[mi][ni] = (f32x4){0.f, 0.f, 0.f, 0.f};

  const int kt = K >> 6;
  for (int t = 0; t < kt; ++t) {
    const int k0 = t * 64;
#pragma unroll
    for (int it = 0; it < 4; ++it) {
      const int chunk_u = it * 256 + (tid & ~63);  // wave-uniform 16B-chunk base
      const int chunk = chunk_u + lane;
      const int row = chunk >> 3;
      const int col = (chunk & 7) * 8;
      __builtin_amdgcn_global_load_lds(
          (GAS unsigned int*)(A + (size_t)(m0 + row) * K + k0 + col),
          (LAS unsigned int*)(As + chunk_u * 8), 16, 0, 0);
      __builtin_amdgcn_global_load_lds(
          (GAS unsigned int*)(Bt + (size_t)(n0 + row) * K + k0 + col),
          (LAS unsigned int*)(Bs + chunk_u * 8), 16, 0, 0);
    }
    __syncthreads();  // drains vmcnt(0) then barrier

#pragma unroll
    for (int kk = 0; kk < 2; ++kk) {
      bf16x8 af[4], bfr[4];
#pragma unroll
      for (int mi = 0; mi < 4; mi++)
        af[mi] = *(const bf16x8*)(As + (wr * 64 + mi * 16 + lr) * 64 + kk * 32 + lg * 8);
#pragma unroll
      for (int ni = 0; ni < 4; ni++)
        bfr[ni] = *(const bf16x8*)(Bs + (wc * 64 + ni * 16 + lr) * 64 + kk * 32 + lg * 8);
#pragma unroll
      for (int mi = 0; mi < 4; mi++)
#pragma unroll
        for (int ni = 0; ni < 4; ni++)
          acc[mi][ni] = __builtin_amdgcn_mfma_f32_16x16x32_bf16(
              af[mi], bfr[ni], acc[mi][ni], 0, 0, 0);
    }
    __syncthreads();  // protect LDS reuse next iter
  }

  // epilogue: C/D layout col = lane&15, row = (lane>>4)*4 + r
#pragma unroll
  for (int mi = 0; mi < 4; mi++) {
#pragma unroll
    for (int ni = 0; ni < 4; ni++) {
      const int nn = n0 + wc * 64 + ni * 16 + lr;
      const float bv = bias[nn];
#pragma unroll
      for (int r = 0; r < 4; r++) {
        const int mm = m0 + wr * 64 + mi * 16 + lg * 4 + r;
        float v = acc[mi][ni][r] + bv;
        if constexpr (MODE == 0) {
          const int b = mm >> 11, tt = mm & 2047;
          const int which = nn >> 10, c = nn & 1023;
          const int h = c >> 6, d = c & 63;
          size_t off;
          if (which == 2)
            off = ((size_t)(b * 16 + h) * 64 + d) * 2048 + tt;   // V^T [B,H,D,T]
          else
            off = ((size_t)(b * 16 + h) * 2048 + tt) * 64 + d;   // Q,K [B,H,T,D]
          unsigned short* dst = (which == 0) ? Oq : ((which == 1) ? Ok : Ov);
          dst[off] = f2b(v);
        } else {
          Of[(size_t)mm * N + nn] = v;
        }
      }
    }
  }
}

// ---------------- flash attention (causal) ----------------
// grid: B*H*16 blocks of 256 threads (4 waves). Block `p` handles q-tiles
// (31-p) then (p): uniform 33 KV-tile iterations per block.
// K [64 t][64 d] and V^T [64 d][64 t] tiles staged via global_load_lds with
// XOR-swizzle (linear LDS dest + pre-swizzled global source column; reads
// XOR ((row&7)<<3)). Double-buffered: one barrier per tile.

__global__ void __launch_bounds__(256) attn_kernel(
    const unsigned short* __restrict__ Qh, const unsigned short* __restrict__ Kh,
    const unsigned short* __restrict__ Vh, unsigned short* __restrict__ yatt) {
  __shared__ unsigned short KsL[2 * 64 * 64];
  __shared__ unsigned short VsL[2 * 64 * 64];
  __shared__ unsigned short Pl[4 * 16 * 72];

  const int tid = threadIdx.x;
  const int lane = tid & 63;
  const int w = tid >> 6;
  const int lr = lane & 15, lg = lane >> 4;

  const int pair = blockIdx.x & 15;
  const int hh = (blockIdx.x >> 4) & 15;
  const int bb = blockIdx.x >> 8;

  const int qtA = 31 - pair;   // long phase first
  const int qtB = pair;
  const int ntA = qtA + 1, ntB = qtB + 1, total = ntA + ntB;

  const size_t head_base = ((size_t)(bb * 16 + hh)) * 2048 * 64;
  const unsigned short* Qg = Qh + head_base;
  const unsigned short* Kg = Kh + head_base;
  const unsigned short* Vg = Vh + head_base;  // [D=64][T=2048] within head

  const int q0A = qtA * 64 + w * 16;
  const int q0B = qtB * 64 + w * 16;

  bf16x8 aqA0 = *(const bf16x8*)(Qg + (size_t)(q0A + lr) * 64 + lg * 8);
  bf16x8 aqA1 = *(const bf16x8*)(Qg + (size_t)(q0A + lr) * 64 + 32 + lg * 8);
  bf16x8 aqB0 = *(const bf16x8*)(Qg + (size_t)(q0B + lr) * 64 + lg * 8);
  bf16x8 aqB1 = *(const bf16x8*)(Qg + (size_t)(q0B + lr) * 64 + 32 + lg * 8);

  float m_run[4], l_run[4];
  f32x4 acc_o[4];
#pragma unroll
  for (int r = 0; r < 4; r++) { m_run[r] = -__builtin_inff(); l_run[r] = 0.f; }
#pragma unroll
  for (int dj = 0; dj < 4; dj++) acc_o[dj] = (f32x4){0.f, 0.f, 0.f, 0.f};

  const float SCL = 0.125f * 1.44269504088896340736f;  // 1/sqrt(64) * log2(e)

  const int sub = lane >> 3;
  const int srccol = (((lane & 7) ^ sub) << 3);  // pre-swizzled global column

  // stage one KV tile (kv0) into buffer `buf` — 4 global_load_lds per wave
  auto stage = [&](int kv0, int buf) {
    unsigned short* Kd = KsL + buf * (64 * 64);
    unsigned short* Vd = VsL + buf * (64 * 64);
#pragma unroll
    for (int it = 0; it < 2; ++it) {
      const int r0 = it * 32 + w * 8;
      const int row = r0 + sub;
      __builtin_amdgcn_global_load_lds(
          (GAS unsigned int*)(Kg + (size_t)(kv0 + row) * 64 + srccol),
          (LAS unsigned int*)(Kd + r0 * 64), 16, 0, 0);
      __builtin_amdgcn_global_load_lds(
          (GAS unsigned int*)(Vg + (size_t)row * 2048 + kv0 + srccol),
          (LAS unsigned int*)(Vd + r0 * 64), 16, 0, 0);
    }
  };

  unsigned short* Pw = Pl + w * 16 * 72;
  const int swr = (lr & 7) << 3;  // read-side XOR for rows with row&7 == lr&7

  stage(0, 0);
  __syncthreads();

  for (int i = 0; i < total; ++i) {
    const int cur = i & 1;
    if (i + 1 < total) {
      const int nkv = (i + 1 < ntA) ? (i + 1) : (i + 1 - ntA);
      stage(nkv * 64, cur ^ 1);
    }

    const bool isA = (i < ntA);
    const int kv0 = (isA ? i : (i - ntA)) * 64;
    const int q0 = isA ? q0A : q0B;
    const bf16x8 a0 = isA ? aqA0 : aqB0;
    const bf16x8 a1 = isA ? aqA1 : aqB1;

    const unsigned short* Kb = KsL + cur * (64 * 64);
    const unsigned short* Vb = VsL + cur * (64 * 64);

    // QK^T: S[16 q rows][64 keys]
    f32x4 s[4];
#pragma unroll
    for (int nj = 0; nj < 4; nj++) {
      const unsigned short* krow = Kb + (nj * 16 + lr) * 64;
      bf16x8 kb0 = *(const bf16x8*)(krow + ((lg * 8) ^ swr));
      bf16x8 kb1 = *(const bf16x8*)(krow + ((32 + lg * 8) ^ swr));
      f32x4 z = (f32x4){0.f, 0.f, 0.f, 0.f};
      z = __builtin_amdgcn_mfma_f32_16x16x32_bf16(a0, kb0, z, 0, 0, 0);
      z = __builtin_amdgcn_mfma_f32_16x16x32_bf16(a1, kb1, z, 0, 0, 0);
      s[nj] = z;
    }

    // causal mask + wave-parallel online softmax (log2 domain)
    float sv[4][4], pm[4];
#pragma unroll
    for (int r = 0; r < 4; r++) pm[r] = -__builtin_inff();
#pragma unroll
    for (int nj = 0; nj < 4; nj++) {
      const int key = kv0 + nj * 16 + lr;
#pragma unroll
      for (int r = 0; r < 4; r++) {
        const int qrow = q0 + lg * 4 + r;
        float v = s[nj][r] * SCL;
        v = (key <= qrow) ? v : -__builtin_inff();
        sv[nj][r] = v;
        pm[r] = fmaxf(pm[r], v);
      }
    }
#pragma unroll
    for (int r = 0; r < 4; r++) {
#pragma unroll
      for (int off = 1; off < 16; off <<= 1)
        pm[r] = fmaxf(pm[r], __shfl_xor(pm[r], off));
    }
    float scale[4], rs[4];
#pragma unroll
    for (int r = 0; r < 4; r++) {
      const float mn = fmaxf(m_run[r], pm[r]);
      scale[r] = exp2f(m_run[r] - mn);  // 0 on first tile (m_run=-inf)
      m_run[r] = mn;
      rs[r] = 0.f;
    }
#pragma unroll
    for (int nj = 0; nj < 4; nj++) {
#pragma unroll
      for (int r = 0; r < 4; r++) {
        const float p = exp2f(sv[nj][r] - m_run[r]);  // masked -> exp2(-inf)=0
        rs[r] += p;
        Pw[(lg * 4 + r) * 72 + nj * 16 + lr] = f2b(p);
      }
    }
#pragma unroll
    for (int r = 0; r < 4; r++) {
#pragma unroll
      for (int off = 1; off < 16; off <<= 1) rs[r] += __shfl_xor(rs[r], off);
      l_run[r] = l_run[r] * scale[r] + rs[r];
#pragma unroll
      for (int dj = 0; dj < 4; dj++) acc_o[dj][r] *= scale[r];
    }

    // PV: O += P[16,64] * V^T[64 d][64 t]
    bf16x8 pa0 = *(const bf16x8*)(Pw + lr * 72 + lg * 8);
    bf16x8 pa1 = *(const bf16x8*)(Pw + lr * 72 + 32 + lg * 8);
#pragma unroll
    for (int dj = 0; dj < 4; dj++) {
      const unsigned short* vrow = Vb + (dj * 16 + lr) * 64;
      bf16x8 vb0 = *(const bf16x8*)(vrow + ((lg * 8) ^ swr));
      bf16x8 vb1 = *(const bf16x8*)(vrow + ((32 + lg * 8) ^ swr));
      acc_o[dj] = __builtin_amdgcn_mfma_f32_16x16x32_bf16(pa0, vb0, acc_o[dj], 0, 0, 0);
      acc_o[dj] = __builtin_amdgcn_mfma_f32_16x16x32_bf16(pa1, vb1, acc_o[dj], 0, 0, 0);
    }

    // phase-A epilogue + state reset (once, mid-kernel)
    if (i == ntA - 1) {
#pragma unroll
      for (int r = 0; r < 4; r++) {
        const float inv = 1.0f / l_run[r];
        const int t = q0A + lg * 4 + r;
        const size_t rowbase = ((size_t)(bb * 2048 + t)) * 1024 + hh * 64;
#pragma unroll
        for (int dj = 0; dj < 4; dj++)
          yatt[rowbase + dj * 16 + lr] = f2b(acc_o[dj][r] * inv);
        m_run[r] = -__builtin_inff();
        l_run[r] = 0.f;
      }
#pragma unroll
      for (int dj = 0; dj < 4; dj++) acc_o[dj] = (f32x4){0.f, 0.f, 0.f, 0.f};
    }

    __syncthreads();  // drains next-tile loads; protects buf reuse
  }

  // phase-B epilogue
#pragma unroll
  for (int r = 0; r < 4; r++) {
    const float inv = 1.0f / l_run[r];
    const int t = q0B + lg * 4 + r;
    const size_t rowbase = ((size_t)(bb * 2048 + t)) * 1024 + hh * 64;
#pragma unroll
    for (int dj = 0; dj < 4; dj++)
      yatt[rowbase + dj * 16 + lr] = f2b(acc_o[dj][r] * inv);
  }
}

// ---------------- launcher ----------------

extern "C" void kernel_launch(void* const* d_in, const int* in_sizes, int n_in,
                              void* d_out, int out_size, void* d_ws,
                              size_t ws_size, hipStream_t stream) {
  (void)in_sizes; (void)n_in; (void)out_size; (void)ws_size;
  const float* x      = (const float*)d_in[0];  // [2,2048,1024]
  const float* w_qkv  = (const float*)d_in[1];  // [1024,3072]
  const float* b_qkv  = (const float*)d_in[2];  // [3072]
  const float* w_proj = (const float*)d_in[3];  // [1024,1024]
  const float* b_proj = (const float*)d_in[4];  // [1024]
  float* out = (float*)d_out;                   // [2,2048,1024] f32

  unsigned short* ws     = (unsigned short*)d_ws;
  unsigned short* xb     = ws;                                  // 4096*1024
  unsigned short* wqkvT  = xb     + (size_t)4096 * 1024;        // 3072*1024
  unsigned short* wprojT = wqkvT  + (size_t)3072 * 1024;        // 1024*1024
  unsigned short* Qh     = wprojT + (size_t)1024 * 1024;        // 2*16*2048*64
  unsigned short* Kh     = Qh     + (size_t)2 * 16 * 2048 * 64;
  unsigned short* Vh     = Kh     + (size_t)2 * 16 * 2048 * 64; // [B,H,D,T]
  unsigned short* yatt   = Vh     + (size_t)2 * 16 * 2048 * 64; // 4096*1024

  cvt_f32_to_bf16<<<4096, 256, 0, stream>>>(x, xb, 1048576);
  transpose_f32_to_bf16<<<dim3(96, 32), dim3(32, 8), 0, stream>>>(w_qkv, wqkvT, 1024, 3072);
  transpose_f32_to_bf16<<<dim3(32, 32), dim3(32, 8), 0, stream>>>(w_proj, wprojT, 1024, 1024);

  gemm_bt<0><<<dim3(32, 24), 256, 0, stream>>>(xb, wqkvT, b_qkv, Qh, Kh, Vh,
                                               nullptr, 4096, 3072, 1024);
  attn_kernel<<<512, 256, 0, stream>>>(Qh, Kh, Vh, yatt);
  gemm_bt<1><<<dim3(32, 8), 256, 0, stream>>>(yatt, wprojT, b_proj, nullptr,
                                              nullptr, nullptr, out, 4096, 1024, 1024);
}

// Round 3
// 164.544 us; speedup vs baseline: 1.6489x; 1.1100x over previous
//
#include <hip/hip_runtime.h>

// ---------------------------------------------------------------------------
// CausalSelfAttention: x@Wqkv -> split heads -> causal flash attn -> @Wproj
// B=2 T=2048 C=1024 H=16 D=64. All matmuls bf16 MFMA (16x16x32), f32 accum.
// Round 3: attn VALU diet — scale folded into Q (GEMM epilogue), diag-only
// masking, native bf16 converts, defer-max (T13), unpaired LPT grid (1024
// blocks, 3 blocks/CU).
// ---------------------------------------------------------------------------

typedef __attribute__((ext_vector_type(8))) __bf16 bf16x8;
typedef __attribute__((ext_vector_type(4))) float f32x4;
typedef __attribute__((ext_vector_type(8))) unsigned short u16x8;
typedef __attribute__((ext_vector_type(4))) unsigned short u16x4;

#define GAS __attribute__((address_space(1)))
#define LAS __attribute__((address_space(3)))

__device__ __forceinline__ unsigned short f2b(float f) {
  unsigned int u = __float_as_uint(f);
  unsigned int r = 0x7FFFu + ((u >> 16) & 1u);
  return (unsigned short)((u + r) >> 16);
}

// ---------------- prep kernels ----------------

__global__ void cvt_f32_to_bf16(const float* __restrict__ src,
                                unsigned short* __restrict__ dst, int n4) {
  int i = blockIdx.x * blockDim.x + threadIdx.x;
  if (i < n4) {
    float4 v = ((const float4*)src)[i];
    u16x4 o = { f2b(v.x), f2b(v.y), f2b(v.z), f2b(v.w) };
    *(u16x4*)(dst + (size_t)i * 4) = o;
  }
}

// src [K][N] f32  ->  dst [N][K] bf16
__global__ void transpose_f32_to_bf16(const float* __restrict__ src,
                                      unsigned short* __restrict__ dst,
                                      int K, int N) {
  __shared__ float tile[32][33];
  int n0 = blockIdx.x * 32, k0 = blockIdx.y * 32;
  int tx = threadIdx.x, ty = threadIdx.y;  // 32 x 8
#pragma unroll
  for (int i = 0; i < 32; i += 8)
    tile[ty + i][tx] = src[(size_t)(k0 + ty + i) * N + n0 + tx];
  __syncthreads();
#pragma unroll
  for (int i = 0; i < 32; i += 8)
    dst[(size_t)(n0 + ty + i) * K + k0 + tx] = f2b(tile[tx][ty + i]);
}

// ---------------- GEMM: C = A[M,K] * B^T[N,K]^T + bias ----------------
// m97 structure: 128x128 tile, BK=64, 4 waves, global_load_lds width 16.
// MODE 0: QKV epilogue -> Q (pre-scaled by 1/sqrt(D)*log2e), K as [B,H,T,D];
//         V as [B,H,D,T] (transposed)
// MODE 1: proj epilogue -> f32 natural [M,N]

template <int MODE>
__global__ void __launch_bounds__(256) gemm_bt(
    const unsigned short* __restrict__ A, const unsigned short* __restrict__ Bt,
    const float* __restrict__ bias,
    unsigned short* __restrict__ Oq, unsigned short* __restrict__ Ok,
    unsigned short* __restrict__ Ov, float* __restrict__ Of,
    int M, int N, int K) {
  __shared__ unsigned short As[128 * 64];
  __shared__ unsigned short Bs[128 * 64];

  const int tid = threadIdx.x;
  const int lane = tid & 63;
  const int wid = tid >> 6;
  const int wr = wid >> 1, wc = wid & 1;
  const int lr = lane & 15, lg = lane >> 4;
  const int m0 = blockIdx.x * 128;
  const int n0 = blockIdx.y * 128;

  f32x4 acc[4][4];
#pragma unroll
  for (int mi = 0; mi < 4; mi++)
#pragma unroll
    for (int ni = 0; ni < 4; ni++) acc[mi][ni] = (f32x4){0.f, 0.f, 0.f, 0.f};

  const int kt = K >> 6;
  for (int t = 0; t < kt; ++t) {
    const int k0 = t * 64;
#pragma unroll
    for (int it = 0; it < 4; ++it) {
      const int chunk_u = it * 256 + (tid & ~63);  // wave-uniform 16B-chunk base
      const int chunk = chunk_u + lane;
      const int row = chunk >> 3;
      const int col = (chunk & 7) * 8;
      __builtin_amdgcn_global_load_lds(
          (GAS unsigned int*)(A + (size_t)(m0 + row) * K + k0 + col),
          (LAS unsigned int*)(As + chunk_u * 8), 16, 0, 0);
      __builtin_amdgcn_global_load_lds(
          (GAS unsigned int*)(Bt + (size_t)(n0 + row) * K + k0 + col),
          (LAS unsigned int*)(Bs + chunk_u * 8), 16, 0, 0);
    }
    __syncthreads();  // drains vmcnt(0) then barrier

#pragma unroll
    for (int kk = 0; kk < 2; ++kk) {
      bf16x8 af[4], bfr[4];
#pragma unroll
      for (int mi = 0; mi < 4; mi++)
        af[mi] = *(const bf16x8*)(As + (wr * 64 + mi * 16 + lr) * 64 + kk * 32 + lg * 8);
#pragma unroll
      for (int ni = 0; ni < 4; ni++)
        bfr[ni] = *(const bf16x8*)(Bs + (wc * 64 + ni * 16 + lr) * 64 + kk * 32 + lg * 8);
#pragma unroll
      for (int mi = 0; mi < 4; mi++)
#pragma unroll
        for (int ni = 0; ni < 4; ni++)
          acc[mi][ni] = __builtin_amdgcn_mfma_f32_16x16x32_bf16(
              af[mi], bfr[ni], acc[mi][ni], 0, 0, 0);
    }
    __syncthreads();  // protect LDS reuse next iter
  }

  const float SCLQ = 0.125f * 1.44269504088896340736f;  // 1/sqrt(64)*log2(e)

  // epilogue: C/D layout col = lane&15, row = (lane>>4)*4 + r
#pragma unroll
  for (int mi = 0; mi < 4; mi++) {
#pragma unroll
    for (int ni = 0; ni < 4; ni++) {
      const int nn = n0 + wc * 64 + ni * 16 + lr;
      const float bv = bias[nn];
#pragma unroll
      for (int r = 0; r < 4; r++) {
        const int mm = m0 + wr * 64 + mi * 16 + lg * 4 + r;
        float v = acc[mi][ni][r] + bv;
        if constexpr (MODE == 0) {
          const int b = mm >> 11, tt = mm & 2047;
          const int which = nn >> 10, c = nn & 1023;
          const int h = c >> 6, d = c & 63;
          size_t off;
          if (which == 2)
            off = ((size_t)(b * 16 + h) * 64 + d) * 2048 + tt;   // V^T [B,H,D,T]
          else
            off = ((size_t)(b * 16 + h) * 2048 + tt) * 64 + d;   // Q,K [B,H,T,D]
          if (which == 0) v *= SCLQ;                              // fold QK scale
          unsigned short* dst = (which == 0) ? Oq : ((which == 1) ? Ok : Ov);
          dst[off] = f2b(v);
        } else {
          Of[(size_t)mm * N + nn] = v;
        }
      }
    }
  }
}

// ---------------- flash attention (causal) ----------------
// grid: 1024 blocks = 32 qt_ranks (descending work, LPT) x 32 (b,h).
// blockIdx = rank*32 + bh keeps same-head blocks on the same XCD (rr map).
// K [64 t][64 d] and V^T [64 d][64 t] staged via global_load_lds with
// XOR-swizzle (pre-swizzled global source column; reads XOR ((row&7)<<3)).
// Double-buffered, one barrier per tile. Softmax in log2 domain, scale
// pre-folded into Q. Defer-max (THR=8): skip rescale when max stable.

__global__ void __launch_bounds__(256) attn_kernel(
    const unsigned short* __restrict__ Qh, const unsigned short* __restrict__ Kh,
    const unsigned short* __restrict__ Vh, unsigned short* __restrict__ yatt) {
  __shared__ unsigned short KsL[2 * 64 * 64];
  __shared__ unsigned short VsL[2 * 64 * 64];
  __shared__ unsigned short Pl[4 * 16 * 72];

  const int tid = threadIdx.x;
  const int lane = tid & 63;
  const int w = tid >> 6;
  const int lr = lane & 15, lg = lane >> 4;

  const int bh = blockIdx.x & 31;
  const int qt = 31 - (blockIdx.x >> 5);  // descending work (LPT)
  const int hh = bh & 15;
  const int bb = bh >> 4;
  const int ntiles = qt + 1;

  const size_t head_base = ((size_t)(bb * 16 + hh)) * 2048 * 64;
  const unsigned short* Qg = Qh + head_base;
  const unsigned short* Kg = Kh + head_base;
  const unsigned short* Vg = Vh + head_base;  // [D=64][T=2048] within head

  const int q0 = qt * 64 + w * 16;

  bf16x8 aq0 = *(const bf16x8*)(Qg + (size_t)(q0 + lr) * 64 + lg * 8);
  bf16x8 aq1 = *(const bf16x8*)(Qg + (size_t)(q0 + lr) * 64 + 32 + lg * 8);

  float m_run[4], l_run[4];
  f32x4 acc_o[4];
#pragma unroll
  for (int r = 0; r < 4; r++) { m_run[r] = -__builtin_inff(); l_run[r] = 0.f; }
#pragma unroll
  for (int dj = 0; dj < 4; dj++) acc_o[dj] = (f32x4){0.f, 0.f, 0.f, 0.f};

  const int sub = lane >> 3;
  const int srccol = (((lane & 7) ^ sub) << 3);  // pre-swizzled global column

  auto stage = [&](int kv0, int buf) {
    unsigned short* Kd = KsL + buf * (64 * 64);
    unsigned short* Vd = VsL + buf * (64 * 64);
#pragma unroll
    for (int it = 0; it < 2; ++it) {
      const int r0 = it * 32 + w * 8;
      const int row = r0 + sub;
      __builtin_amdgcn_global_load_lds(
          (GAS unsigned int*)(Kg + (size_t)(kv0 + row) * 64 + srccol),
          (LAS unsigned int*)(Kd + r0 * 64), 16, 0, 0);
      __builtin_amdgcn_global_load_lds(
          (GAS unsigned int*)(Vg + (size_t)row * 2048 + kv0 + srccol),
          (LAS unsigned int*)(Vd + r0 * 64), 16, 0, 0);
    }
  };

  __bf16* Pw = (__bf16*)(Pl + w * 16 * 72);
  const int swr = (lr & 7) << 3;  // read-side XOR for row (nj*16+lr)

  stage(0, 0);
  __syncthreads();

  for (int i = 0; i < ntiles; ++i) {
    const int cur = i & 1;
    if (i + 1 < ntiles) stage((i + 1) * 64, cur ^ 1);

    const int kv0 = i * 64;
    const unsigned short* Kb = KsL + cur * (64 * 64);
    const unsigned short* Vb = VsL + cur * (64 * 64);

    // QK^T (pre-scaled, log2 domain): S[16 q rows][64 keys]
    f32x4 s[4];
#pragma unroll
    for (int nj = 0; nj < 4; nj++) {
      const unsigned short* krow = Kb + (nj * 16 + lr) * 64;
      bf16x8 kb0 = *(const bf16x8*)(krow + ((lg * 8) ^ swr));
      bf16x8 kb1 = *(const bf16x8*)(krow + ((32 + lg * 8) ^ swr));
      f32x4 z = (f32x4){0.f, 0.f, 0.f, 0.f};
      z = __builtin_amdgcn_mfma_f32_16x16x32_bf16(aq0, kb0, z, 0, 0, 0);
      z = __builtin_amdgcn_mfma_f32_16x16x32_bf16(aq1, kb1, z, 0, 0, 0);
      s[nj] = z;
    }

    // causal mask: only the diagonal tile needs it (wave-uniform branch)
    if (i == ntiles - 1) {
#pragma unroll
      for (int nj = 0; nj < 4; nj++) {
        const int key = kv0 + nj * 16 + lr;
#pragma unroll
        for (int r = 0; r < 4; r++) {
          const int qrow = q0 + lg * 4 + r;
          if (key > qrow) s[nj][r] = -__builtin_inff();
        }
      }
    }

    // per-row max over this tile
    float pm[4];
#pragma unroll
    for (int r = 0; r < 4; r++)
      pm[r] = fmaxf(fmaxf(s[0][r], s[1][r]), fmaxf(s[2][r], s[3][r]));
#pragma unroll
    for (int r = 0; r < 4; r++) {
#pragma unroll
      for (int off = 1; off < 16; off <<= 1)
        pm[r] = fmaxf(pm[r], __shfl_xor(pm[r], off));
    }

    // defer-max (T13): skip rescale when max growth <= 8 (log2 units)
    int stable = (pm[0] <= m_run[0] + 8.f) & (pm[1] <= m_run[1] + 8.f) &
                 (pm[2] <= m_run[2] + 8.f) & (pm[3] <= m_run[3] + 8.f);
    if (!__all(stable)) {
#pragma unroll
      for (int r = 0; r < 4; r++) {
        const float mn = fmaxf(m_run[r], pm[r]);
        const float sc = exp2f(m_run[r] - mn);  // 0 on first tile
        m_run[r] = mn;
        l_run[r] *= sc;
#pragma unroll
        for (int dj = 0; dj < 4; dj++) acc_o[dj][r] *= sc;
      }
    }

    // P = exp2(s - m), accumulate row sums, write P to LDS as bf16
    float rs[4] = {0.f, 0.f, 0.f, 0.f};
#pragma unroll
    for (int nj = 0; nj < 4; nj++) {
#pragma unroll
      for (int r = 0; r < 4; r++) {
        const float p = exp2f(s[nj][r] - m_run[r]);
        rs[r] += p;
        Pw[(lg * 4 + r) * 72 + nj * 16 + lr] = (__bf16)p;
      }
    }
#pragma unroll
    for (int r = 0; r < 4; r++) {
#pragma unroll
      for (int off = 1; off < 16; off <<= 1) rs[r] += __shfl_xor(rs[r], off);
      l_run[r] += rs[r];
    }

    // PV: O += P[16,64] * V^T[64 d][64 t]
    bf16x8 pa0 = *(const bf16x8*)(Pw + lr * 72 + lg * 8);
    bf16x8 pa1 = *(const bf16x8*)(Pw + lr * 72 + 32 + lg * 8);
#pragma unroll
    for (int dj = 0; dj < 4; dj++) {
      const unsigned short* vrow = Vb + (dj * 16 + lr) * 64;
      bf16x8 vb0 = *(const bf16x8*)(vrow + ((lg * 8) ^ swr));
      bf16x8 vb1 = *(const bf16x8*)(vrow + ((32 + lg * 8) ^ swr));
      acc_o[dj] = __builtin_amdgcn_mfma_f32_16x16x32_bf16(pa0, vb0, acc_o[dj], 0, 0, 0);
      acc_o[dj] = __builtin_amdgcn_mfma_f32_16x16x32_bf16(pa1, vb1, acc_o[dj], 0, 0, 0);
    }

    __syncthreads();  // drains next-tile loads; protects buf reuse
  }

  // epilogue: normalize, write bf16 [B,T,C] (heads re-merged)
  __bf16* yb = (__bf16*)yatt;
#pragma unroll
  for (int r = 0; r < 4; r++) {
    const float inv = 1.0f / l_run[r];
    const int t = q0 + lg * 4 + r;
    const size_t rowbase = ((size_t)(bb * 2048 + t)) * 1024 + hh * 64;
#pragma unroll
    for (int dj = 0; dj < 4; dj++)
      yb[rowbase + dj * 16 + lr] = (__bf16)(acc_o[dj][r] * inv);
  }
}

// ---------------- launcher ----------------

extern "C" void kernel_launch(void* const* d_in, const int* in_sizes, int n_in,
                              void* d_out, int out_size, void* d_ws,
                              size_t ws_size, hipStream_t stream) {
  (void)in_sizes; (void)n_in; (void)out_size; (void)ws_size;
  const float* x      = (const float*)d_in[0];  // [2,2048,1024]
  const float* w_qkv  = (const float*)d_in[1];  // [1024,3072]
  const float* b_qkv  = (const float*)d_in[2];  // [3072]
  const float* w_proj = (const float*)d_in[3];  // [1024,1024]
  const float* b_proj = (const float*)d_in[4];  // [1024]
  float* out = (float*)d_out;                   // [2,2048,1024] f32

  unsigned short* ws     = (unsigned short*)d_ws;
  unsigned short* xb     = ws;                                  // 4096*1024
  unsigned short* wqkvT  = xb     + (size_t)4096 * 1024;        // 3072*1024
  unsigned short* wprojT = wqkvT  + (size_t)3072 * 1024;        // 1024*1024
  unsigned short* Qh     = wprojT + (size_t)1024 * 1024;        // 2*16*2048*64
  unsigned short* Kh     = Qh     + (size_t)2 * 16 * 2048 * 64;
  unsigned short* Vh     = Kh     + (size_t)2 * 16 * 2048 * 64; // [B,H,D,T]
  unsigned short* yatt   = Vh     + (size_t)2 * 16 * 2048 * 64; // 4096*1024

  cvt_f32_to_bf16<<<4096, 256, 0, stream>>>(x, xb, 1048576);
  transpose_f32_to_bf16<<<dim3(96, 32), dim3(32, 8), 0, stream>>>(w_qkv, wqkvT, 1024, 3072);
  transpose_f32_to_bf16<<<dim3(32, 32), dim3(32, 8), 0, stream>>>(w_proj, wprojT, 1024, 1024);

  gemm_bt<0><<<dim3(32, 24), 256, 0, stream>>>(xb, wqkvT, b_qkv, Qh, Kh, Vh,
                                               nullptr, 4096, 3072, 1024);
  attn_kernel<<<1024, 256, 0, stream>>>(Qh, Kh, Vh, yatt);
  gemm_bt<1><<<dim3(32, 8), 256, 0, stream>>>(yatt, wprojT, b_proj, nullptr,
                                              nullptr, nullptr, out, 4096, 1024, 1024);
}

// Round 4
// 147.577 us; speedup vs baseline: 1.8385x; 1.1150x over previous
//
#include <hip/hip_runtime.h>

// ---------------------------------------------------------------------------
// CausalSelfAttention: x@Wqkv -> split heads -> causal flash attn -> @Wproj
// B=2 T=2048 C=1024 H=16 D=64. All matmuls bf16 MFMA (16x16x32), f32 accum.
// Round 4: attn latency surgery — lane-local defer-max check (skips the
// 16-lane shfl max butterfly on ~95% of tiles) and row-sum via MFMA with a
// ones B-operand (kills the shfl sum butterfly entirely). No ds_bpermute in
// the steady-state path.
// ---------------------------------------------------------------------------

typedef __attribute__((ext_vector_type(8))) __bf16 bf16x8;
typedef __attribute__((ext_vector_type(4))) float f32x4;
typedef __attribute__((ext_vector_type(8))) unsigned short u16x8;
typedef __attribute__((ext_vector_type(4))) unsigned short u16x4;

#define GAS __attribute__((address_space(1)))
#define LAS __attribute__((address_space(3)))

__device__ __forceinline__ unsigned short f2b(float f) {
  unsigned int u = __float_as_uint(f);
  unsigned int r = 0x7FFFu + ((u >> 16) & 1u);
  return (unsigned short)((u + r) >> 16);
}

// ---------------- prep kernels ----------------

__global__ void cvt_f32_to_bf16(const float* __restrict__ src,
                                unsigned short* __restrict__ dst, int n4) {
  int i = blockIdx.x * blockDim.x + threadIdx.x;
  if (i < n4) {
    float4 v = ((const float4*)src)[i];
    u16x4 o = { f2b(v.x), f2b(v.y), f2b(v.z), f2b(v.w) };
    *(u16x4*)(dst + (size_t)i * 4) = o;
  }
}

// src [K][N] f32  ->  dst [N][K] bf16
__global__ void transpose_f32_to_bf16(const float* __restrict__ src,
                                      unsigned short* __restrict__ dst,
                                      int K, int N) {
  __shared__ float tile[32][33];
  int n0 = blockIdx.x * 32, k0 = blockIdx.y * 32;
  int tx = threadIdx.x, ty = threadIdx.y;  // 32 x 8
#pragma unroll
  for (int i = 0; i < 32; i += 8)
    tile[ty + i][tx] = src[(size_t)(k0 + ty + i) * N + n0 + tx];
  __syncthreads();
#pragma unroll
  for (int i = 0; i < 32; i += 8)
    dst[(size_t)(n0 + ty + i) * K + k0 + tx] = f2b(tile[tx][ty + i]);
}

// ---------------- GEMM: C = A[M,K] * B^T[N,K]^T + bias ----------------
// m97 structure: 128x128 tile, BK=64, 4 waves, global_load_lds width 16.
// MODE 0: QKV epilogue -> Q (pre-scaled by 1/sqrt(D)*log2e), K as [B,H,T,D];
//         V as [B,H,D,T] (transposed)
// MODE 1: proj epilogue -> f32 natural [M,N]

template <int MODE>
__global__ void __launch_bounds__(256) gemm_bt(
    const unsigned short* __restrict__ A, const unsigned short* __restrict__ Bt,
    const float* __restrict__ bias,
    unsigned short* __restrict__ Oq, unsigned short* __restrict__ Ok,
    unsigned short* __restrict__ Ov, float* __restrict__ Of,
    int M, int N, int K) {
  __shared__ unsigned short As[128 * 64];
  __shared__ unsigned short Bs[128 * 64];

  const int tid = threadIdx.x;
  const int lane = tid & 63;
  const int wid = tid >> 6;
  const int wr = wid >> 1, wc = wid & 1;
  const int lr = lane & 15, lg = lane >> 4;
  const int m0 = blockIdx.x * 128;
  const int n0 = blockIdx.y * 128;

  f32x4 acc[4][4];
#pragma unroll
  for (int mi = 0; mi < 4; mi++)
#pragma unroll
    for (int ni = 0; ni < 4; ni++) acc[mi][ni] = (f32x4){0.f, 0.f, 0.f, 0.f};

  const int kt = K >> 6;
  for (int t = 0; t < kt; ++t) {
    const int k0 = t * 64;
#pragma unroll
    for (int it = 0; it < 4; ++it) {
      const int chunk_u = it * 256 + (tid & ~63);  // wave-uniform 16B-chunk base
      const int chunk = chunk_u + lane;
      const int row = chunk >> 3;
      const int col = (chunk & 7) * 8;
      __builtin_amdgcn_global_load_lds(
          (GAS unsigned int*)(A + (size_t)(m0 + row) * K + k0 + col),
          (LAS unsigned int*)(As + chunk_u * 8), 16, 0, 0);
      __builtin_amdgcn_global_load_lds(
          (GAS unsigned int*)(Bt + (size_t)(n0 + row) * K + k0 + col),
          (LAS unsigned int*)(Bs + chunk_u * 8), 16, 0, 0);
    }
    __syncthreads();  // drains vmcnt(0) then barrier

#pragma unroll
    for (int kk = 0; kk < 2; ++kk) {
      bf16x8 af[4], bfr[4];
#pragma unroll
      for (int mi = 0; mi < 4; mi++)
        af[mi] = *(const bf16x8*)(As + (wr * 64 + mi * 16 + lr) * 64 + kk * 32 + lg * 8);
#pragma unroll
      for (int ni = 0; ni < 4; ni++)
        bfr[ni] = *(const bf16x8*)(Bs + (wc * 64 + ni * 16 + lr) * 64 + kk * 32 + lg * 8);
#pragma unroll
      for (int mi = 0; mi < 4; mi++)
#pragma unroll
        for (int ni = 0; ni < 4; ni++)
          acc[mi][ni] = __builtin_amdgcn_mfma_f32_16x16x32_bf16(
              af[mi], bfr[ni], acc[mi][ni], 0, 0, 0);
    }
    __syncthreads();  // protect LDS reuse next iter
  }

  const float SCLQ = 0.125f * 1.44269504088896340736f;  // 1/sqrt(64)*log2(e)

  // epilogue: C/D layout col = lane&15, row = (lane>>4)*4 + r
#pragma unroll
  for (int mi = 0; mi < 4; mi++) {
#pragma unroll
    for (int ni = 0; ni < 4; ni++) {
      const int nn = n0 + wc * 64 + ni * 16 + lr;
      const float bv = bias[nn];
#pragma unroll
      for (int r = 0; r < 4; r++) {
        const int mm = m0 + wr * 64 + mi * 16 + lg * 4 + r;
        float v = acc[mi][ni][r] + bv;
        if constexpr (MODE == 0) {
          const int b = mm >> 11, tt = mm & 2047;
          const int which = nn >> 10, c = nn & 1023;
          const int h = c >> 6, d = c & 63;
          size_t off;
          if (which == 2)
            off = ((size_t)(b * 16 + h) * 64 + d) * 2048 + tt;   // V^T [B,H,D,T]
          else
            off = ((size_t)(b * 16 + h) * 2048 + tt) * 64 + d;   // Q,K [B,H,T,D]
          if (which == 0) v *= SCLQ;                              // fold QK scale
          unsigned short* dst = (which == 0) ? Oq : ((which == 1) ? Ok : Ov);
          dst[off] = f2b(v);
        } else {
          Of[(size_t)mm * N + nn] = v;
        }
      }
    }
  }
}

// ---------------- flash attention (causal) ----------------
// grid: 1024 blocks = 32 qt_ranks (descending work, LPT) x 32 (b,h).
// K [64 t][64 d] and V^T [64 d][64 t] staged via global_load_lds with
// XOR-swizzle. Double-buffered, one barrier per tile. Softmax in log2
// domain, scale pre-folded into Q. Lane-local defer-max (T13, THR=8):
// steady-state path has no cross-lane ops; row-sum via MFMA(P, ones).

__global__ void __launch_bounds__(256) attn_kernel(
    const unsigned short* __restrict__ Qh, const unsigned short* __restrict__ Kh,
    const unsigned short* __restrict__ Vh, unsigned short* __restrict__ yatt) {
  __shared__ unsigned short KsL[2 * 64 * 64];
  __shared__ unsigned short VsL[2 * 64 * 64];
  __shared__ unsigned short Pl[4 * 16 * 72];

  const int tid = threadIdx.x;
  const int lane = tid & 63;
  const int w = tid >> 6;
  const int lr = lane & 15, lg = lane >> 4;

  const int bh = blockIdx.x & 31;
  const int qt = 31 - (blockIdx.x >> 5);  // descending work (LPT)
  const int hh = bh & 15;
  const int bb = bh >> 4;
  const int ntiles = qt + 1;

  const size_t head_base = ((size_t)(bb * 16 + hh)) * 2048 * 64;
  const unsigned short* Qg = Qh + head_base;
  const unsigned short* Kg = Kh + head_base;
  const unsigned short* Vg = Vh + head_base;  // [D=64][T=2048] within head

  const int q0 = qt * 64 + w * 16;

  bf16x8 aq0 = *(const bf16x8*)(Qg + (size_t)(q0 + lr) * 64 + lg * 8);
  bf16x8 aq1 = *(const bf16x8*)(Qg + (size_t)(q0 + lr) * 64 + 32 + lg * 8);

  bf16x8 vones;
#pragma unroll
  for (int j = 0; j < 8; j++) vones[j] = (__bf16)1.0f;

  float m_run[4], l_run[4];
  f32x4 acc_o[4];
#pragma unroll
  for (int r = 0; r < 4; r++) { m_run[r] = -__builtin_inff(); l_run[r] = 0.f; }
#pragma unroll
  for (int dj = 0; dj < 4; dj++) acc_o[dj] = (f32x4){0.f, 0.f, 0.f, 0.f};

  const int sub = lane >> 3;
  const int srccol = (((lane & 7) ^ sub) << 3);  // pre-swizzled global column

  auto stage = [&](int kv0, int buf) {
    unsigned short* Kd = KsL + buf * (64 * 64);
    unsigned short* Vd = VsL + buf * (64 * 64);
#pragma unroll
    for (int it = 0; it < 2; ++it) {
      const int r0 = it * 32 + w * 8;
      const int row = r0 + sub;
      __builtin_amdgcn_global_load_lds(
          (GAS unsigned int*)(Kg + (size_t)(kv0 + row) * 64 + srccol),
          (LAS unsigned int*)(Kd + r0 * 64), 16, 0, 0);
      __builtin_amdgcn_global_load_lds(
          (GAS unsigned int*)(Vg + (size_t)row * 2048 + kv0 + srccol),
          (LAS unsigned int*)(Vd + r0 * 64), 16, 0, 0);
    }
  };

  __bf16* Pw = (__bf16*)(Pl + w * 16 * 72);
  const int swr = (lr & 7) << 3;  // read-side XOR for row (nj*16+lr)

  stage(0, 0);
  __syncthreads();

  for (int i = 0; i < ntiles; ++i) {
    const int cur = i & 1;
    if (i + 1 < ntiles) stage((i + 1) * 64, cur ^ 1);

    const int kv0 = i * 64;
    const unsigned short* Kb = KsL + cur * (64 * 64);
    const unsigned short* Vb = VsL + cur * (64 * 64);

    // QK^T (pre-scaled, log2 domain): S[16 q rows][64 keys]
    f32x4 s[4];
#pragma unroll
    for (int nj = 0; nj < 4; nj++) {
      const unsigned short* krow = Kb + (nj * 16 + lr) * 64;
      bf16x8 kb0 = *(const bf16x8*)(krow + ((lg * 8) ^ swr));
      bf16x8 kb1 = *(const bf16x8*)(krow + ((32 + lg * 8) ^ swr));
      f32x4 z = (f32x4){0.f, 0.f, 0.f, 0.f};
      z = __builtin_amdgcn_mfma_f32_16x16x32_bf16(aq0, kb0, z, 0, 0, 0);
      z = __builtin_amdgcn_mfma_f32_16x16x32_bf16(aq1, kb1, z, 0, 0, 0);
      s[nj] = z;
    }

    // causal mask: only the diagonal tile needs it (wave-uniform branch)
    if (i == ntiles - 1) {
#pragma unroll
      for (int nj = 0; nj < 4; nj++) {
        const int key = kv0 + nj * 16 + lr;
#pragma unroll
        for (int r = 0; r < 4; r++) {
          const int qrow = q0 + lg * 4 + r;
          if (key > qrow) s[nj][r] = -__builtin_inff();
        }
      }
    }

    // lane-local per-row max (keys this lane owns)
    float pm[4];
#pragma unroll
    for (int r = 0; r < 4; r++)
      pm[r] = fmaxf(fmaxf(s[0][r], s[1][r]), fmaxf(s[2][r], s[3][r]));

    // defer-max (T13, THR=8): row max <= m+8 iff ALL lanes' local max does.
    const bool okl = (pm[0] <= m_run[0] + 8.f) & (pm[1] <= m_run[1] + 8.f) &
                     (pm[2] <= m_run[2] + 8.f) & (pm[3] <= m_run[3] + 8.f);
    if (!__all(okl)) {  // rare: first tile + occasional max growth
#pragma unroll
      for (int r = 0; r < 4; r++) {
#pragma unroll
        for (int off = 1; off < 16; off <<= 1)
          pm[r] = fmaxf(pm[r], __shfl_xor(pm[r], off));
        const float mn = fmaxf(m_run[r], pm[r]);
        const float sc = exp2f(m_run[r] - mn);  // 0 on first tile
        m_run[r] = mn;
        l_run[r] *= sc;
#pragma unroll
        for (int dj = 0; dj < 4; dj++) acc_o[dj][r] *= sc;
      }
    }

    // P = exp2(s - m) -> bf16 -> LDS (values bounded by 2^8)
#pragma unroll
    for (int nj = 0; nj < 4; nj++) {
#pragma unroll
      for (int r = 0; r < 4; r++) {
        const float p = exp2f(s[nj][r] - m_run[r]);
        Pw[(lg * 4 + r) * 72 + nj * 16 + lr] = (__bf16)p;
      }
    }

    bf16x8 pa0 = *(const bf16x8*)(Pw + lr * 72 + lg * 8);
    bf16x8 pa1 = *(const bf16x8*)(Pw + lr * 72 + 32 + lg * 8);

    // row sums via MFMA with ones B-operand (replaces shfl butterfly);
    // uses the same bf16-rounded P that feeds PV.
    f32x4 zs = (f32x4){0.f, 0.f, 0.f, 0.f};
    zs = __builtin_amdgcn_mfma_f32_16x16x32_bf16(pa0, vones, zs, 0, 0, 0);
    zs = __builtin_amdgcn_mfma_f32_16x16x32_bf16(pa1, vones, zs, 0, 0, 0);

    // PV: O += P[16,64] * V^T[64 d][64 t]
#pragma unroll
    for (int dj = 0; dj < 4; dj++) {
      const unsigned short* vrow = Vb + (dj * 16 + lr) * 64;
      bf16x8 vb0 = *(const bf16x8*)(vrow + ((lg * 8) ^ swr));
      bf16x8 vb1 = *(const bf16x8*)(vrow + ((32 + lg * 8) ^ swr));
      acc_o[dj] = __builtin_amdgcn_mfma_f32_16x16x32_bf16(pa0, vb0, acc_o[dj], 0, 0, 0);
      acc_o[dj] = __builtin_amdgcn_mfma_f32_16x16x32_bf16(pa1, vb1, acc_o[dj], 0, 0, 0);
    }

#pragma unroll
    for (int r = 0; r < 4; r++) l_run[r] += zs[r];

    __syncthreads();  // drains next-tile loads; protects buf reuse
  }

  // epilogue: normalize, write bf16 [B,T,C] (heads re-merged)
  __bf16* yb = (__bf16*)yatt;
#pragma unroll
  for (int r = 0; r < 4; r++) {
    const float inv = 1.0f / l_run[r];
    const int t = q0 + lg * 4 + r;
    const size_t rowbase = ((size_t)(bb * 2048 + t)) * 1024 + hh * 64;
#pragma unroll
    for (int dj = 0; dj < 4; dj++)
      yb[rowbase + dj * 16 + lr] = (__bf16)(acc_o[dj][r] * inv);
  }
}

// ---------------- launcher ----------------

extern "C" void kernel_launch(void* const* d_in, const int* in_sizes, int n_in,
                              void* d_out, int out_size, void* d_ws,
                              size_t ws_size, hipStream_t stream) {
  (void)in_sizes; (void)n_in; (void)out_size; (void)ws_size;
  const float* x      = (const float*)d_in[0];  // [2,2048,1024]
  const float* w_qkv  = (const float*)d_in[1];  // [1024,3072]
  const float* b_qkv  = (const float*)d_in[2];  // [3072]
  const float* w_proj = (const float*)d_in[3];  // [1024,1024]
  const float* b_proj = (const float*)d_in[4];  // [1024]
  float* out = (float*)d_out;                   // [2,2048,1024] f32

  unsigned short* ws     = (unsigned short*)d_ws;
  unsigned short* xb     = ws;                                  // 4096*1024
  unsigned short* wqkvT  = xb     + (size_t)4096 * 1024;        // 3072*1024
  unsigned short* wprojT = wqkvT  + (size_t)3072 * 1024;        // 1024*1024
  unsigned short* Qh     = wprojT + (size_t)1024 * 1024;        // 2*16*2048*64
  unsigned short* Kh     = Qh     + (size_t)2 * 16 * 2048 * 64;
  unsigned short* Vh     = Kh     + (size_t)2 * 16 * 2048 * 64; // [B,H,D,T]
  unsigned short* yatt   = Vh     + (size_t)2 * 16 * 2048 * 64; // 4096*1024

  cvt_f32_to_bf16<<<4096, 256, 0, stream>>>(x, xb, 1048576);
  transpose_f32_to_bf16<<<dim3(96, 32), dim3(32, 8), 0, stream>>>(w_qkv, wqkvT, 1024, 3072);
  transpose_f32_to_bf16<<<dim3(32, 32), dim3(32, 8), 0, stream>>>(w_proj, wprojT, 1024, 1024);

  gemm_bt<0><<<dim3(32, 24), 256, 0, stream>>>(xb, wqkvT, b_qkv, Qh, Kh, Vh,
                                               nullptr, 4096, 3072, 1024);
  attn_kernel<<<1024, 256, 0, stream>>>(Qh, Kh, Vh, yatt);
  gemm_bt<1><<<dim3(32, 8), 256, 0, stream>>>(yatt, wprojT, b_proj, nullptr,
                                              nullptr, nullptr, out, 4096, 1024, 1024);
}

// Round 5
// 127.351 us; speedup vs baseline: 2.1305x; 1.1588x over previous
//
#include <hip/hip_runtime.h>

// ---------------------------------------------------------------------------
// CausalSelfAttention: x@Wqkv -> split heads -> causal flash attn -> @Wproj
// B=2 T=2048 C=1024 H=16 D=64. All matmuls bf16 MFMA (16x16x32), f32 accum.
// Round 5: GEMM pipeline surgery — double-buffered LDS + raw s_barrier with
// COUNTED s_waitcnt vmcnt(8) (prefetch stays in flight across barriers, T4),
// and (row&7)-XOR LDS swizzle on A/B tiles (T2, both-sides, proven in attn).
// Attn staging loop gets the same counted-vmcnt treatment (vmcnt(4)).
// ---------------------------------------------------------------------------

typedef __attribute__((ext_vector_type(8))) __bf16 bf16x8;
typedef __attribute__((ext_vector_type(4))) float f32x4;
typedef __attribute__((ext_vector_type(8))) unsigned short u16x8;
typedef __attribute__((ext_vector_type(4))) unsigned short u16x4;

#define GAS __attribute__((address_space(1)))
#define LAS __attribute__((address_space(3)))

__device__ __forceinline__ unsigned short f2b(float f) {
  unsigned int u = __float_as_uint(f);
  unsigned int r = 0x7FFFu + ((u >> 16) & 1u);
  return (unsigned short)((u + r) >> 16);
}

// ---------------- prep kernels ----------------

__global__ void cvt_f32_to_bf16(const float* __restrict__ src,
                                unsigned short* __restrict__ dst, int n4) {
  int i = blockIdx.x * blockDim.x + threadIdx.x;
  if (i < n4) {
    float4 v = ((const float4*)src)[i];
    u16x4 o = { f2b(v.x), f2b(v.y), f2b(v.z), f2b(v.w) };
    *(u16x4*)(dst + (size_t)i * 4) = o;
  }
}

// src [K][N] f32  ->  dst [N][K] bf16
__global__ void transpose_f32_to_bf16(const float* __restrict__ src,
                                      unsigned short* __restrict__ dst,
                                      int K, int N) {
  __shared__ float tile[32][33];
  int n0 = blockIdx.x * 32, k0 = blockIdx.y * 32;
  int tx = threadIdx.x, ty = threadIdx.y;  // 32 x 8
#pragma unroll
  for (int i = 0; i < 32; i += 8)
    tile[ty + i][tx] = src[(size_t)(k0 + ty + i) * N + n0 + tx];
  __syncthreads();
#pragma unroll
  for (int i = 0; i < 32; i += 8)
    dst[(size_t)(n0 + ty + i) * K + k0 + tx] = f2b(tile[tx][ty + i]);
}

// ---------------- GEMM: C = A[M,K] * B^T[N,K]^T + bias ----------------
// 128x128 tile, BK=64, 4 waves. Double-buffered LDS, counted vmcnt(8),
// (row&7)-XOR swizzled A/B tiles (linear LDS dest, pre-swizzled source).
// MODE 0: QKV epilogue -> Q (pre-scaled by 1/sqrt(D)*log2e), K as [B,H,T,D];
//         V as [B,H,D,T] (transposed)
// MODE 1: proj epilogue -> f32 natural [M,N]

template <int MODE>
__global__ void __launch_bounds__(256) gemm_bt(
    const unsigned short* __restrict__ A, const unsigned short* __restrict__ Bt,
    const float* __restrict__ bias,
    unsigned short* __restrict__ Oq, unsigned short* __restrict__ Ok,
    unsigned short* __restrict__ Ov, float* __restrict__ Of,
    int M, int N, int K) {
  __shared__ unsigned short As[2 * 128 * 64];
  __shared__ unsigned short Bs[2 * 128 * 64];

  const int tid = threadIdx.x;
  const int lane = tid & 63;
  const int wid = tid >> 6;
  const int wr = wid >> 1, wc = wid & 1;
  const int lr = lane & 15, lg = lane >> 4;
  const int m0 = blockIdx.x * 128;
  const int n0 = blockIdx.y * 128;

  f32x4 acc[4][4];
#pragma unroll
  for (int mi = 0; mi < 4; mi++)
#pragma unroll
    for (int ni = 0; ni < 4; ni++) acc[mi][ni] = (f32x4){0.f, 0.f, 0.f, 0.f};

  // stage K-tile t into buffer buf: 8 global_load_lds per thread.
  // Source column pre-swizzled by (row&7); LDS dest linear (rule #21).
  auto stage = [&](int t, int buf) {
    const int k0 = t * 64;
    unsigned short* Ad = As + buf * (128 * 64);
    unsigned short* Bd = Bs + buf * (128 * 64);
#pragma unroll
    for (int it = 0; it < 4; ++it) {
      const int chunk_u = it * 256 + (tid & ~63);  // wave-uniform 16B-chunk base
      const int chunk = chunk_u + lane;
      const int row = chunk >> 3;
      const int col = ((chunk & 7) ^ (row & 7)) * 8;  // pre-swizzled src col
      __builtin_amdgcn_global_load_lds(
          (GAS unsigned int*)(A + (size_t)(m0 + row) * K + k0 + col),
          (LAS unsigned int*)(Ad + chunk_u * 8), 16, 0, 0);
      __builtin_amdgcn_global_load_lds(
          (GAS unsigned int*)(Bt + (size_t)(n0 + row) * K + k0 + col),
          (LAS unsigned int*)(Bd + chunk_u * 8), 16, 0, 0);
    }
  };

  const int swa = (lr & 7) * 8;  // read-side XOR (row&7 == lr&7 for our rows)
  const int kt = K >> 6;

  stage(0, 0);

  for (int t = 0; t < kt; ++t) {
    const int cur = t & 1;
    __builtin_amdgcn_s_barrier();        // A: everyone done reading buf cur^1
    if (t + 1 < kt) {
      stage(t + 1, cur ^ 1);             // prefetch stays in flight (T4)
      asm volatile("s_waitcnt vmcnt(8)" ::: "memory");  // tile-t loads done
    } else {
      asm volatile("s_waitcnt vmcnt(0)" ::: "memory");
    }
    __builtin_amdgcn_s_barrier();        // B: tile t visible to all waves

    const unsigned short* Ab = As + cur * (128 * 64);
    const unsigned short* Bb = Bs + cur * (128 * 64);

#pragma unroll
    for (int kk = 0; kk < 2; ++kk) {
      bf16x8 af[4], bfr[4];
#pragma unroll
      for (int mi = 0; mi < 4; mi++)
        af[mi] = *(const bf16x8*)(Ab + (wr * 64 + mi * 16 + lr) * 64 +
                                  ((kk * 32 + lg * 8) ^ swa));
#pragma unroll
      for (int ni = 0; ni < 4; ni++)
        bfr[ni] = *(const bf16x8*)(Bb + (wc * 64 + ni * 16 + lr) * 64 +
                                   ((kk * 32 + lg * 8) ^ swa));
#pragma unroll
      for (int mi = 0; mi < 4; mi++)
#pragma unroll
        for (int ni = 0; ni < 4; ni++)
          acc[mi][ni] = __builtin_amdgcn_mfma_f32_16x16x32_bf16(
              af[mi], bfr[ni], acc[mi][ni], 0, 0, 0);
    }
  }

  const float SCLQ = 0.125f * 1.44269504088896340736f;  // 1/sqrt(64)*log2(e)

  // epilogue: C/D layout col = lane&15, row = (lane>>4)*4 + r
#pragma unroll
  for (int mi = 0; mi < 4; mi++) {
#pragma unroll
    for (int ni = 0; ni < 4; ni++) {
      const int nn = n0 + wc * 64 + ni * 16 + lr;
      const float bv = bias[nn];
#pragma unroll
      for (int r = 0; r < 4; r++) {
        const int mm = m0 + wr * 64 + mi * 16 + lg * 4 + r;
        float v = acc[mi][ni][r] + bv;
        if constexpr (MODE == 0) {
          const int b = mm >> 11, tt = mm & 2047;
          const int which = nn >> 10, c = nn & 1023;
          const int h = c >> 6, d = c & 63;
          size_t off;
          if (which == 2)
            off = ((size_t)(b * 16 + h) * 64 + d) * 2048 + tt;   // V^T [B,H,D,T]
          else
            off = ((size_t)(b * 16 + h) * 2048 + tt) * 64 + d;   // Q,K [B,H,T,D]
          if (which == 0) v *= SCLQ;                              // fold QK scale
          unsigned short* dst = (which == 0) ? Oq : ((which == 1) ? Ok : Ov);
          dst[off] = f2b(v);
        } else {
          Of[(size_t)mm * N + nn] = v;
        }
      }
    }
  }
}

// ---------------- flash attention (causal) ----------------
// grid: 1024 blocks = 32 qt_ranks (descending work, LPT) x 32 (b,h).
// K [64 t][64 d] and V^T [64 d][64 t] staged via global_load_lds with
// XOR-swizzle. Double-buffered with counted vmcnt(4) (prefetch in flight
// across barriers). Softmax in log2 domain, scale pre-folded into Q.
// Lane-local defer-max (T13, THR=8); row-sum via MFMA(P, ones).

__global__ void __launch_bounds__(256) attn_kernel(
    const unsigned short* __restrict__ Qh, const unsigned short* __restrict__ Kh,
    const unsigned short* __restrict__ Vh, unsigned short* __restrict__ yatt) {
  __shared__ unsigned short KsL[2 * 64 * 64];
  __shared__ unsigned short VsL[2 * 64 * 64];
  __shared__ unsigned short Pl[4 * 16 * 72];

  const int tid = threadIdx.x;
  const int lane = tid & 63;
  const int w = tid >> 6;
  const int lr = lane & 15, lg = lane >> 4;

  const int bh = blockIdx.x & 31;
  const int qt = 31 - (blockIdx.x >> 5);  // descending work (LPT)
  const int hh = bh & 15;
  const int bb = bh >> 4;
  const int ntiles = qt + 1;

  const size_t head_base = ((size_t)(bb * 16 + hh)) * 2048 * 64;
  const unsigned short* Qg = Qh + head_base;
  const unsigned short* Kg = Kh + head_base;
  const unsigned short* Vg = Vh + head_base;  // [D=64][T=2048] within head

  const int q0 = qt * 64 + w * 16;

  bf16x8 aq0 = *(const bf16x8*)(Qg + (size_t)(q0 + lr) * 64 + lg * 8);
  bf16x8 aq1 = *(const bf16x8*)(Qg + (size_t)(q0 + lr) * 64 + 32 + lg * 8);

  bf16x8 vones;
#pragma unroll
  for (int j = 0; j < 8; j++) vones[j] = (__bf16)1.0f;

  float m_run[4], l_run[4];
  f32x4 acc_o[4];
#pragma unroll
  for (int r = 0; r < 4; r++) { m_run[r] = -__builtin_inff(); l_run[r] = 0.f; }
#pragma unroll
  for (int dj = 0; dj < 4; dj++) acc_o[dj] = (f32x4){0.f, 0.f, 0.f, 0.f};

  const int sub = lane >> 3;
  const int srccol = (((lane & 7) ^ sub) << 3);  // pre-swizzled global column

  auto stage = [&](int kv0, int buf) {
    unsigned short* Kd = KsL + buf * (64 * 64);
    unsigned short* Vd = VsL + buf * (64 * 64);
#pragma unroll
    for (int it = 0; it < 2; ++it) {
      const int r0 = it * 32 + w * 8;
      const int row = r0 + sub;
      __builtin_amdgcn_global_load_lds(
          (GAS unsigned int*)(Kg + (size_t)(kv0 + row) * 64 + srccol),
          (LAS unsigned int*)(Kd + r0 * 64), 16, 0, 0);
      __builtin_amdgcn_global_load_lds(
          (GAS unsigned int*)(Vg + (size_t)row * 2048 + kv0 + srccol),
          (LAS unsigned int*)(Vd + r0 * 64), 16, 0, 0);
    }
  };

  __bf16* Pw = (__bf16*)(Pl + w * 16 * 72);
  const int swr = (lr & 7) << 3;  // read-side XOR for row (nj*16+lr)

  stage(0, 0);

  for (int i = 0; i < ntiles; ++i) {
    const int cur = i & 1;
    __builtin_amdgcn_s_barrier();        // A: protect buf cur^1
    if (i + 1 < ntiles) {
      stage((i + 1) * 64, cur ^ 1);      // prefetch stays in flight (T4)
      asm volatile("s_waitcnt vmcnt(4)" ::: "memory");  // tile-i loads done
    } else {
      asm volatile("s_waitcnt vmcnt(0)" ::: "memory");
    }
    __builtin_amdgcn_s_barrier();        // B: tile i visible

    const int kv0 = i * 64;
    const unsigned short* Kb = KsL + cur * (64 * 64);
    const unsigned short* Vb = VsL + cur * (64 * 64);

    // QK^T (pre-scaled, log2 domain): S[16 q rows][64 keys]
    f32x4 s[4];
#pragma unroll
    for (int nj = 0; nj < 4; nj++) {
      const unsigned short* krow = Kb + (nj * 16 + lr) * 64;
      bf16x8 kb0 = *(const bf16x8*)(krow + ((lg * 8) ^ swr));
      bf16x8 kb1 = *(const bf16x8*)(krow + ((32 + lg * 8) ^ swr));
      f32x4 z = (f32x4){0.f, 0.f, 0.f, 0.f};
      z = __builtin_amdgcn_mfma_f32_16x16x32_bf16(aq0, kb0, z, 0, 0, 0);
      z = __builtin_amdgcn_mfma_f32_16x16x32_bf16(aq1, kb1, z, 0, 0, 0);
      s[nj] = z;
    }

    // causal mask: only the diagonal tile needs it (wave-uniform branch)
    if (i == ntiles - 1) {
#pragma unroll
      for (int nj = 0; nj < 4; nj++) {
        const int key = kv0 + nj * 16 + lr;
#pragma unroll
        for (int r = 0; r < 4; r++) {
          const int qrow = q0 + lg * 4 + r;
          if (key > qrow) s[nj][r] = -__builtin_inff();
        }
      }
    }

    // lane-local per-row max (keys this lane owns)
    float pm[4];
#pragma unroll
    for (int r = 0; r < 4; r++)
      pm[r] = fmaxf(fmaxf(s[0][r], s[1][r]), fmaxf(s[2][r], s[3][r]));

    // defer-max (T13, THR=8): row max <= m+8 iff ALL lanes' local max does.
    const bool okl = (pm[0] <= m_run[0] + 8.f) & (pm[1] <= m_run[1] + 8.f) &
                     (pm[2] <= m_run[2] + 8.f) & (pm[3] <= m_run[3] + 8.f);
    if (!__all(okl)) {  // rare: first tile + occasional max growth
#pragma unroll
      for (int r = 0; r < 4; r++) {
#pragma unroll
        for (int off = 1; off < 16; off <<= 1)
          pm[r] = fmaxf(pm[r], __shfl_xor(pm[r], off));
        const float mn = fmaxf(m_run[r], pm[r]);
        const float sc = exp2f(m_run[r] - mn);  // 0 on first tile
        m_run[r] = mn;
        l_run[r] *= sc;
#pragma unroll
        for (int dj = 0; dj < 4; dj++) acc_o[dj][r] *= sc;
      }
    }

    // P = exp2(s - m) -> bf16 -> LDS (values bounded by 2^8)
#pragma unroll
    for (int nj = 0; nj < 4; nj++) {
#pragma unroll
      for (int r = 0; r < 4; r++) {
        const float p = exp2f(s[nj][r] - m_run[r]);
        Pw[(lg * 4 + r) * 72 + nj * 16 + lr] = (__bf16)p;
      }
    }

    bf16x8 pa0 = *(const bf16x8*)(Pw + lr * 72 + lg * 8);
    bf16x8 pa1 = *(const bf16x8*)(Pw + lr * 72 + 32 + lg * 8);

    // row sums via MFMA with ones B-operand (replaces shfl butterfly)
    f32x4 zs = (f32x4){0.f, 0.f, 0.f, 0.f};
    zs = __builtin_amdgcn_mfma_f32_16x16x32_bf16(pa0, vones, zs, 0, 0, 0);
    zs = __builtin_amdgcn_mfma_f32_16x16x32_bf16(pa1, vones, zs, 0, 0, 0);

    // PV: O += P[16,64] * V^T[64 d][64 t]
#pragma unroll
    for (int dj = 0; dj < 4; dj++) {
      const unsigned short* vrow = Vb + (dj * 16 + lr) * 64;
      bf16x8 vb0 = *(const bf16x8*)(vrow + ((lg * 8) ^ swr));
      bf16x8 vb1 = *(const bf16x8*)(vrow + ((32 + lg * 8) ^ swr));
      acc_o[dj] = __builtin_amdgcn_mfma_f32_16x16x32_bf16(pa0, vb0, acc_o[dj], 0, 0, 0);
      acc_o[dj] = __builtin_amdgcn_mfma_f32_16x16x32_bf16(pa1, vb1, acc_o[dj], 0, 0, 0);
    }

#pragma unroll
    for (int r = 0; r < 4; r++) l_run[r] += zs[r];
  }

  // epilogue: normalize, write bf16 [B,T,C] (heads re-merged)
  __bf16* yb = (__bf16*)yatt;
#pragma unroll
  for (int r = 0; r < 4; r++) {
    const float inv = 1.0f / l_run[r];
    const int t = q0 + lg * 4 + r;
    const size_t rowbase = ((size_t)(bb * 2048 + t)) * 1024 + hh * 64;
#pragma unroll
    for (int dj = 0; dj < 4; dj++)
      yb[rowbase + dj * 16 + lr] = (__bf16)(acc_o[dj][r] * inv);
  }
}

// ---------------- launcher ----------------

extern "C" void kernel_launch(void* const* d_in, const int* in_sizes, int n_in,
                              void* d_out, int out_size, void* d_ws,
                              size_t ws_size, hipStream_t stream) {
  (void)in_sizes; (void)n_in; (void)out_size; (void)ws_size;
  const float* x      = (const float*)d_in[0];  // [2,2048,1024]
  const float* w_qkv  = (const float*)d_in[1];  // [1024,3072]
  const float* b_qkv  = (const float*)d_in[2];  // [3072]
  const float* w_proj = (const float*)d_in[3];  // [1024,1024]
  const float* b_proj = (const float*)d_in[4];  // [1024]
  float* out = (float*)d_out;                   // [2,2048,1024] f32

  unsigned short* ws     = (unsigned short*)d_ws;
  unsigned short* xb     = ws;                                  // 4096*1024
  unsigned short* wqkvT  = xb     + (size_t)4096 * 1024;        // 3072*1024
  unsigned short* wprojT = wqkvT  + (size_t)3072 * 1024;        // 1024*1024
  unsigned short* Qh     = wprojT + (size_t)1024 * 1024;        // 2*16*2048*64
  unsigned short* Kh     = Qh     + (size_t)2 * 16 * 2048 * 64;
  unsigned short* Vh     = Kh     + (size_t)2 * 16 * 2048 * 64; // [B,H,D,T]
  unsigned short* yatt   = Vh     + (size_t)2 * 16 * 2048 * 64; // 4096*1024

  cvt_f32_to_bf16<<<4096, 256, 0, stream>>>(x, xb, 1048576);
  transpose_f32_to_bf16<<<dim3(96, 32), dim3(32, 8), 0, stream>>>(w_qkv, wqkvT, 1024, 3072);
  transpose_f32_to_bf16<<<dim3(32, 32), dim3(32, 8), 0, stream>>>(w_proj, wprojT, 1024, 1024);

  gemm_bt<0><<<dim3(32, 24), 256, 0, stream>>>(xb, wqkvT, b_qkv, Qh, Kh, Vh,
                                               nullptr, 4096, 3072, 1024);
  attn_kernel<<<1024, 256, 0, stream>>>(Qh, Kh, Vh, yatt);
  gemm_bt<1><<<dim3(32, 8), 256, 0, stream>>>(yatt, wprojT, b_proj, nullptr,
                                              nullptr, nullptr, out, 4096, 1024, 1024);
}

// Round 6
// 124.334 us; speedup vs baseline: 2.1822x; 1.0243x over previous
//
#include <hip/hip_runtime.h>

// ---------------------------------------------------------------------------
// CausalSelfAttention: x@Wqkv -> split heads -> causal flash attn -> @Wproj
// B=2 T=2048 C=1024 H=16 D=64. All matmuls bf16 MFMA (16x16x32), f32 accum.
// Round 6: (a) QKV epilogue v2 — LDS re-stage + fully coalesced 16B writes
// (no scattered 2B stores, no 4KB-stride V^T scatter); (b) attn QBLK=128,
// 8 waves / 512 threads, 50KB LDS -> 3 blocks/CU, staging halved.
// ---------------------------------------------------------------------------

typedef __attribute__((ext_vector_type(8))) __bf16 bf16x8;
typedef __attribute__((ext_vector_type(4))) float f32x4;
typedef __attribute__((ext_vector_type(8))) unsigned short u16x8;
typedef __attribute__((ext_vector_type(4))) unsigned short u16x4;

#define GAS __attribute__((address_space(1)))
#define LAS __attribute__((address_space(3)))

__device__ __forceinline__ unsigned short f2b(float f) {
  unsigned int u = __float_as_uint(f);
  unsigned int r = 0x7FFFu + ((u >> 16) & 1u);
  return (unsigned short)((u + r) >> 16);
}

// ---------------- prep kernels ----------------

__global__ void cvt_f32_to_bf16(const float* __restrict__ src,
                                unsigned short* __restrict__ dst, int n4) {
  int i = blockIdx.x * blockDim.x + threadIdx.x;
  if (i < n4) {
    float4 v = ((const float4*)src)[i];
    u16x4 o = { f2b(v.x), f2b(v.y), f2b(v.z), f2b(v.w) };
    *(u16x4*)(dst + (size_t)i * 4) = o;
  }
}

// src [K][N] f32  ->  dst [N][K] bf16
__global__ void transpose_f32_to_bf16(const float* __restrict__ src,
                                      unsigned short* __restrict__ dst,
                                      int K, int N) {
  __shared__ float tile[32][33];
  int n0 = blockIdx.x * 32, k0 = blockIdx.y * 32;
  int tx = threadIdx.x, ty = threadIdx.y;  // 32 x 8
#pragma unroll
  for (int i = 0; i < 32; i += 8)
    tile[ty + i][tx] = src[(size_t)(k0 + ty + i) * N + n0 + tx];
  __syncthreads();
#pragma unroll
  for (int i = 0; i < 32; i += 8)
    dst[(size_t)(n0 + ty + i) * K + k0 + tx] = f2b(tile[tx][ty + i]);
}

// ---------------- GEMM: C = A[M,K] * B^T[N,K]^T + bias ----------------
// 128x128 tile, BK=64, 4 waves. Double-buffered LDS, counted vmcnt(8),
// (row&7)-XOR swizzled A/B tiles (linear LDS dest, pre-swizzled source).
// MODE 0: QKV epilogue -> Q (pre-scaled by 1/sqrt(D)*log2e), K as [B,H,T,D];
//         V as [B,H,D,T] (transposed). All writes re-staged through LDS and
//         emitted as 128B-contiguous 16B vector stores.
// MODE 1: proj epilogue -> f32 natural [M,N]

template <int MODE>
__global__ void __launch_bounds__(256) gemm_bt(
    const unsigned short* __restrict__ A, const unsigned short* __restrict__ Bt,
    const float* __restrict__ bias,
    unsigned short* __restrict__ Oq, unsigned short* __restrict__ Ok,
    unsigned short* __restrict__ Ov, float* __restrict__ Of,
    int M, int N, int K) {
  __shared__ unsigned short smem[4 * 128 * 64];  // 64 KB: As dbuf | Bs dbuf
  unsigned short* As = smem;
  unsigned short* Bs = smem + 2 * 128 * 64;

  const int tid = threadIdx.x;
  const int lane = tid & 63;
  const int wid = tid >> 6;
  const int wr = wid >> 1, wc = wid & 1;
  const int lr = lane & 15, lg = lane >> 4;
  const int m0 = blockIdx.x * 128;
  const int n0 = blockIdx.y * 128;

  f32x4 acc[4][4];
#pragma unroll
  for (int mi = 0; mi < 4; mi++)
#pragma unroll
    for (int ni = 0; ni < 4; ni++) acc[mi][ni] = (f32x4){0.f, 0.f, 0.f, 0.f};

  // stage K-tile t into buffer buf: 8 global_load_lds per thread.
  auto stage = [&](int t, int buf) {
    const int k0 = t * 64;
    unsigned short* Ad = As + buf * (128 * 64);
    unsigned short* Bd = Bs + buf * (128 * 64);
#pragma unroll
    for (int it = 0; it < 4; ++it) {
      const int chunk_u = it * 256 + (tid & ~63);  // wave-uniform 16B-chunk base
      const int chunk = chunk_u + lane;
      const int row = chunk >> 3;
      const int col = ((chunk & 7) ^ (row & 7)) * 8;  // pre-swizzled src col
      __builtin_amdgcn_global_load_lds(
          (GAS unsigned int*)(A + (size_t)(m0 + row) * K + k0 + col),
          (LAS unsigned int*)(Ad + chunk_u * 8), 16, 0, 0);
      __builtin_amdgcn_global_load_lds(
          (GAS unsigned int*)(Bt + (size_t)(n0 + row) * K + k0 + col),
          (LAS unsigned int*)(Bd + chunk_u * 8), 16, 0, 0);
    }
  };

  const int swa = (lr & 7) * 8;  // read-side XOR (row&7 == lr&7 for our rows)
  const int kt = K >> 6;

  stage(0, 0);

  for (int t = 0; t < kt; ++t) {
    const int cur = t & 1;
    __builtin_amdgcn_s_barrier();        // A: everyone done reading buf cur^1
    if (t + 1 < kt) {
      stage(t + 1, cur ^ 1);             // prefetch stays in flight (T4)
      asm volatile("s_waitcnt vmcnt(8)" ::: "memory");  // tile-t loads done
    } else {
      asm volatile("s_waitcnt vmcnt(0)" ::: "memory");
    }
    __builtin_amdgcn_s_barrier();        // B: tile t visible to all waves

    const unsigned short* Ab = As + cur * (128 * 64);
    const unsigned short* Bb = Bs + cur * (128 * 64);

#pragma unroll
    for (int kk = 0; kk < 2; ++kk) {
      bf16x8 af[4], bfr[4];
#pragma unroll
      for (int mi = 0; mi < 4; mi++)
        af[mi] = *(const bf16x8*)(Ab + (wr * 64 + mi * 16 + lr) * 64 +
                                  ((kk * 32 + lg * 8) ^ swa));
#pragma unroll
      for (int ni = 0; ni < 4; ni++)
        bfr[ni] = *(const bf16x8*)(Bb + (wc * 64 + ni * 16 + lr) * 64 +
                                   ((kk * 32 + lg * 8) ^ swa));
#pragma unroll
      for (int mi = 0; mi < 4; mi++)
#pragma unroll
        for (int ni = 0; ni < 4; ni++)
          acc[mi][ni] = __builtin_amdgcn_mfma_f32_16x16x32_bf16(
              af[mi], bfr[ni], acc[mi][ni], 0, 0, 0);
    }
  }

  const float SCLQ = 0.125f * 1.44269504088896340736f;  // 1/sqrt(64)*log2(e)

  if constexpr (MODE == 1) {
    // proj epilogue: direct f32 stores (64B-contiguous per lane group)
#pragma unroll
    for (int mi = 0; mi < 4; mi++) {
#pragma unroll
      for (int ni = 0; ni < 4; ni++) {
        const int nn = n0 + wc * 64 + ni * 16 + lr;
        const float bv = bias[nn];
#pragma unroll
        for (int r = 0; r < 4; r++) {
          const int mm = m0 + wr * 64 + mi * 16 + lg * 4 + r;
          Of[(size_t)mm * N + nn] = acc[mi][ni][r] + bv;
        }
      }
    }
  } else {
    // QKV epilogue v2: re-stage through LDS (reuse smem), write coalesced.
    unsigned short* L = smem;            // [128][136] bf16 (pad breaks banks)
    const int which = n0 >> 10;          // block-uniform third (0=Q,1=K,2=V)
    const float sc = (which == 0) ? SCLQ : 1.0f;
    __syncthreads();                     // all waves done reading As/Bs
#pragma unroll
    for (int mi = 0; mi < 4; mi++) {
#pragma unroll
      for (int ni = 0; ni < 4; ni++) {
        const int nn_l = wc * 64 + ni * 16 + lr;
        const float bv = bias[n0 + nn_l];
#pragma unroll
        for (int r = 0; r < 4; r++) {
          const int mm_l = wr * 64 + mi * 16 + lg * 4 + r;
          const unsigned short v = f2b((acc[mi][ni][r] + bv) * sc);
          if (which == 2) L[nn_l * 136 + mm_l] = v;   // V: store transposed
          else            L[mm_l * 136 + nn_l] = v;   // Q,K: natural
        }
      }
    }
    __syncthreads();
    // readout: 256 threads x one 128B contiguous row-piece (8x16B stores)
    const int b = m0 >> 11;
    const int t0 = m0 & 2047;
    const int h0 = (n0 & 1023) >> 6;
    if (which == 2) {
      const int row = tid >> 1;          // (hsub,d): 2 heads x 64 d
      const int hsub = row >> 6, d = row & 63;
      const int tt0 = (tid & 1) * 64;
      const unsigned short* src = L + row * 136 + tt0;
      unsigned short* dst = Ov +
          ((size_t)((b * 16 + h0 + hsub) * 64 + d)) * 2048 + t0 + tt0;
#pragma unroll
      for (int j = 0; j < 8; j++)
        *(u16x8*)(dst + j * 8) = *(const u16x8*)(src + j * 8);
    } else {
      const int mm_l = tid & 127;
      const int hsub = tid >> 7;
      const unsigned short* src = L + mm_l * 136 + hsub * 64;
      unsigned short* base = (which == 0) ? Oq : Ok;
      unsigned short* dst = base +
          ((size_t)(b * 16 + h0 + hsub) * 2048 + t0 + mm_l) * 64;
#pragma unroll
      for (int j = 0; j < 8; j++)
        *(u16x8*)(dst + j * 8) = *(const u16x8*)(src + j * 8);
    }
  }
}

// ---------------- flash attention (causal) ----------------
// grid: 512 blocks = 16 qt_ranks (descending, LPT) x 32 (b,h); 512 threads
// (8 waves x 16 q-rows = 128 q-rows/block). K [64 t][64 d] and V^T [64 d]
// [64 t] staged via global_load_lds with XOR-swizzle, double-buffered,
// counted vmcnt(2). One staged tile serves all 8 waves. Waves skip fully
// masked tiles (wave-uniform; still hit barriers). Softmax log2-domain,
// scale pre-folded into Q; lane-local defer-max; row-sum via MFMA(P,ones).

__global__ void __launch_bounds__(512) attn_kernel(
    const unsigned short* __restrict__ Qh, const unsigned short* __restrict__ Kh,
    const unsigned short* __restrict__ Vh, unsigned short* __restrict__ yatt) {
  __shared__ unsigned short KsL[2 * 64 * 64];
  __shared__ unsigned short VsL[2 * 64 * 64];
  __shared__ unsigned short Pl[8 * 16 * 72];

  const int tid = threadIdx.x;
  const int lane = tid & 63;
  const int w = tid >> 6;                 // 0..7
  const int lr = lane & 15, lg = lane >> 4;

  const int bh = blockIdx.x & 31;
  const int qt = 15 - (blockIdx.x >> 5);  // descending work (LPT), QBLK=128
  const int hh = bh & 15;
  const int bb = bh >> 4;
  const int ntiles = 2 * qt + 2;          // KV tiles of 64
  const int diagw = 2 * qt + ((w >> 2) & 1);  // wave's diagonal tile index

  const size_t head_base = ((size_t)(bb * 16 + hh)) * 2048 * 64;
  const unsigned short* Qg = Qh + head_base;
  const unsigned short* Kg = Kh + head_base;
  const unsigned short* Vg = Vh + head_base;  // [D=64][T=2048] within head

  const int q0 = qt * 128 + w * 16;

  bf16x8 aq0 = *(const bf16x8*)(Qg + (size_t)(q0 + lr) * 64 + lg * 8);
  bf16x8 aq1 = *(const bf16x8*)(Qg + (size_t)(q0 + lr) * 64 + 32 + lg * 8);

  bf16x8 vones;
#pragma unroll
  for (int j = 0; j < 8; j++) vones[j] = (__bf16)1.0f;

  float m_run[4], l_run[4];
  f32x4 acc_o[4];
#pragma unroll
  for (int r = 0; r < 4; r++) { m_run[r] = -__builtin_inff(); l_run[r] = 0.f; }
#pragma unroll
  for (int dj = 0; dj < 4; dj++) acc_o[dj] = (f32x4){0.f, 0.f, 0.f, 0.f};

  // staging: 512 threads x 1 chunk each per array (row = tid>>3)
  const int srow = tid >> 3;
  const int scol = (((tid & 7) ^ (srow & 7)) << 3);  // pre-swizzled src col

  auto stage = [&](int kv0, int buf) {
    unsigned short* Kd = KsL + buf * (64 * 64);
    unsigned short* Vd = VsL + buf * (64 * 64);
    const int base_u = (tid & ~63) * 8;   // wave-uniform LDS chunk base
    __builtin_amdgcn_global_load_lds(
        (GAS unsigned int*)(Kg + (size_t)(kv0 + srow) * 64 + scol),
        (LAS unsigned int*)(Kd + base_u), 16, 0, 0);
    __builtin_amdgcn_global_load_lds(
        (GAS unsigned int*)(Vg + (size_t)srow * 2048 + kv0 + scol),
        (LAS unsigned int*)(Vd + base_u), 16, 0, 0);
  };

  __bf16* Pw = (__bf16*)(Pl + w * 16 * 72);
  const int swr = (lr & 7) << 3;  // read-side XOR for row (nj*16+lr)

  stage(0, 0);

  for (int i = 0; i < ntiles; ++i) {
    const int cur = i & 1;
    __builtin_amdgcn_s_barrier();        // A: protect buf cur^1
    if (i + 1 < ntiles) {
      stage((i + 1) * 64, cur ^ 1);      // prefetch stays in flight (T4)
      asm volatile("s_waitcnt vmcnt(2)" ::: "memory");  // tile-i loads done
    } else {
      asm volatile("s_waitcnt vmcnt(0)" ::: "memory");
    }
    __builtin_amdgcn_s_barrier();        // B: tile i visible

    if (i <= diagw) {                    // wave-uniform: skip masked tiles
      const int kv0 = i * 64;
      const unsigned short* Kb = KsL + cur * (64 * 64);
      const unsigned short* Vb = VsL + cur * (64 * 64);

      // QK^T (pre-scaled, log2 domain): S[16 q rows][64 keys]
      f32x4 s[4];
#pragma unroll
      for (int nj = 0; nj < 4; nj++) {
        const unsigned short* krow = Kb + (nj * 16 + lr) * 64;
        bf16x8 kb0 = *(const bf16x8*)(krow + ((lg * 8) ^ swr));
        bf16x8 kb1 = *(const bf16x8*)(krow + ((32 + lg * 8) ^ swr));
        f32x4 z = (f32x4){0.f, 0.f, 0.f, 0.f};
        z = __builtin_amdgcn_mfma_f32_16x16x32_bf16(aq0, kb0, z, 0, 0, 0);
        z = __builtin_amdgcn_mfma_f32_16x16x32_bf16(aq1, kb1, z, 0, 0, 0);
        s[nj] = z;
      }

      // causal mask only on the wave's diagonal tile
      if (i == diagw) {
#pragma unroll
        for (int nj = 0; nj < 4; nj++) {
          const int key = kv0 + nj * 16 + lr;
#pragma unroll
          for (int r = 0; r < 4; r++) {
            const int qrow = q0 + lg * 4 + r;
            if (key > qrow) s[nj][r] = -__builtin_inff();
          }
        }
      }

      // lane-local per-row max
      float pm[4];
#pragma unroll
      for (int r = 0; r < 4; r++)
        pm[r] = fmaxf(fmaxf(s[0][r], s[1][r]), fmaxf(s[2][r], s[3][r]));

      // defer-max (T13, THR=8)
      const bool okl = (pm[0] <= m_run[0] + 8.f) & (pm[1] <= m_run[1] + 8.f) &
                       (pm[2] <= m_run[2] + 8.f) & (pm[3] <= m_run[3] + 8.f);
      if (!__all(okl)) {
#pragma unroll
        for (int r = 0; r < 4; r++) {
#pragma unroll
          for (int off = 1; off < 16; off <<= 1)
            pm[r] = fmaxf(pm[r], __shfl_xor(pm[r], off));
          const float mn = fmaxf(m_run[r], pm[r]);
          const float sc = exp2f(m_run[r] - mn);
          m_run[r] = mn;
          l_run[r] *= sc;
#pragma unroll
          for (int dj = 0; dj < 4; dj++) acc_o[dj][r] *= sc;
        }
      }

      // P = exp2(s - m) -> bf16 -> LDS
#pragma unroll
      for (int nj = 0; nj < 4; nj++) {
#pragma unroll
        for (int r = 0; r < 4; r++) {
          const float p = exp2f(s[nj][r] - m_run[r]);
          Pw[(lg * 4 + r) * 72 + nj * 16 + lr] = (__bf16)p;
        }
      }

      bf16x8 pa0 = *(const bf16x8*)(Pw + lr * 72 + lg * 8);
      bf16x8 pa1 = *(const bf16x8*)(Pw + lr * 72 + 32 + lg * 8);

      // row sums via MFMA(P, ones)
      f32x4 zs = (f32x4){0.f, 0.f, 0.f, 0.f};
      zs = __builtin_amdgcn_mfma_f32_16x16x32_bf16(pa0, vones, zs, 0, 0, 0);
      zs = __builtin_amdgcn_mfma_f32_16x16x32_bf16(pa1, vones, zs, 0, 0, 0);

      // PV: O += P[16,64] * V^T[64 d][64 t]
#pragma unroll
      for (int dj = 0; dj < 4; dj++) {
        const unsigned short* vrow = Vb + (dj * 16 + lr) * 64;
        bf16x8 vb0 = *(const bf16x8*)(vrow + ((lg * 8) ^ swr));
        bf16x8 vb1 = *(const bf16x8*)(vrow + ((32 + lg * 8) ^ swr));
        acc_o[dj] = __builtin_amdgcn_mfma_f32_16x16x32_bf16(pa0, vb0, acc_o[dj], 0, 0, 0);
        acc_o[dj] = __builtin_amdgcn_mfma_f32_16x16x32_bf16(pa1, vb1, acc_o[dj], 0, 0, 0);
      }

#pragma unroll
      for (int r = 0; r < 4; r++) l_run[r] += zs[r];
    }
  }

  // epilogue: normalize, write bf16 [B,T,C] (heads re-merged)
  __bf16* yb = (__bf16*)yatt;
#pragma unroll
  for (int r = 0; r < 4; r++) {
    const float inv = 1.0f / l_run[r];
    const int t = q0 + lg * 4 + r;
    const size_t rowbase = ((size_t)(bb * 2048 + t)) * 1024 + hh * 64;
#pragma unroll
    for (int dj = 0; dj < 4; dj++)
      yb[rowbase + dj * 16 + lr] = (__bf16)(acc_o[dj][r] * inv);
  }
}

// ---------------- launcher ----------------

extern "C" void kernel_launch(void* const* d_in, const int* in_sizes, int n_in,
                              void* d_out, int out_size, void* d_ws,
                              size_t ws_size, hipStream_t stream) {
  (void)in_sizes; (void)n_in; (void)out_size; (void)ws_size;
  const float* x      = (const float*)d_in[0];  // [2,2048,1024]
  const float* w_qkv  = (const float*)d_in[1];  // [1024,3072]
  const float* b_qkv  = (const float*)d_in[2];  // [3072]
  const float* w_proj = (const float*)d_in[3];  // [1024,1024]
  const float* b_proj = (const float*)d_in[4];  // [1024]
  float* out = (float*)d_out;                   // [2,2048,1024] f32

  unsigned short* ws     = (unsigned short*)d_ws;
  unsigned short* xb     = ws;                                  // 4096*1024
  unsigned short* wqkvT  = xb     + (size_t)4096 * 1024;        // 3072*1024
  unsigned short* wprojT = wqkvT  + (size_t)3072 * 1024;        // 1024*1024
  unsigned short* Qh     = wprojT + (size_t)1024 * 1024;        // 2*16*2048*64
  unsigned short* Kh     = Qh     + (size_t)2 * 16 * 2048 * 64;
  unsigned short* Vh     = Kh     + (size_t)2 * 16 * 2048 * 64; // [B,H,D,T]
  unsigned short* yatt   = Vh     + (size_t)2 * 16 * 2048 * 64; // 4096*1024

  cvt_f32_to_bf16<<<4096, 256, 0, stream>>>(x, xb, 1048576);
  transpose_f32_to_bf16<<<dim3(96, 32), dim3(32, 8), 0, stream>>>(w_qkv, wqkvT, 1024, 3072);
  transpose_f32_to_bf16<<<dim3(32, 32), dim3(32, 8), 0, stream>>>(w_proj, wprojT, 1024, 1024);

  gemm_bt<0><<<dim3(32, 24), 256, 0, stream>>>(xb, wqkvT, b_qkv, Qh, Kh, Vh,
                                               nullptr, 4096, 3072, 1024);
  attn_kernel<<<512, 512, 0, stream>>>(Qh, Kh, Vh, yatt);
  gemm_bt<1><<<dim3(32, 8), 256, 0, stream>>>(yatt, wprojT, b_proj, nullptr,
                                              nullptr, nullptr, out, 4096, 1024, 1024);
}

// Round 7
// 121.160 us; speedup vs baseline: 2.2393x; 1.0262x over previous
//
#include <hip/hip_runtime.h>

// ---------------------------------------------------------------------------
// CausalSelfAttention: x@Wqkv -> split heads -> causal flash attn -> @Wproj
// B=2 T=2048 C=1024 H=16 D=64. All matmuls bf16 MFMA (16x16x32), f32 accum.
// Round 7: attn KV-split — qt>=4 blocks split into equal L/R KV halves that
// write unnormalized partials (bf16 O + f32 m,l) into dead ws; attn_merge
// combines. 896 balanced blocks -> 3 blocks/CU resident (was 2, 25% occ).
// + T5 setprio around MFMA clusters.
// ---------------------------------------------------------------------------

typedef __attribute__((ext_vector_type(8))) __bf16 bf16x8;
typedef __attribute__((ext_vector_type(4))) float f32x4;
typedef __attribute__((ext_vector_type(8))) unsigned short u16x8;
typedef __attribute__((ext_vector_type(4))) unsigned short u16x4;

#define GAS __attribute__((address_space(1)))
#define LAS __attribute__((address_space(3)))

__device__ __forceinline__ unsigned short f2b(float f) {
  unsigned int u = __float_as_uint(f);
  unsigned int r = 0x7FFFu + ((u >> 16) & 1u);
  return (unsigned short)((u + r) >> 16);
}
__device__ __forceinline__ float b2f(unsigned short u) {
  return __uint_as_float((unsigned int)u << 16);
}

// ---------------- prep kernels ----------------

__global__ void cvt_f32_to_bf16(const float* __restrict__ src,
                                unsigned short* __restrict__ dst, int n4) {
  int i = blockIdx.x * blockDim.x + threadIdx.x;
  if (i < n4) {
    float4 v = ((const float4*)src)[i];
    u16x4 o = { f2b(v.x), f2b(v.y), f2b(v.z), f2b(v.w) };
    *(u16x4*)(dst + (size_t)i * 4) = o;
  }
}

// src [K][N] f32  ->  dst [N][K] bf16
__global__ void transpose_f32_to_bf16(const float* __restrict__ src,
                                      unsigned short* __restrict__ dst,
                                      int K, int N) {
  __shared__ float tile[32][33];
  int n0 = blockIdx.x * 32, k0 = blockIdx.y * 32;
  int tx = threadIdx.x, ty = threadIdx.y;  // 32 x 8
#pragma unroll
  for (int i = 0; i < 32; i += 8)
    tile[ty + i][tx] = src[(size_t)(k0 + ty + i) * N + n0 + tx];
  __syncthreads();
#pragma unroll
  for (int i = 0; i < 32; i += 8)
    dst[(size_t)(n0 + ty + i) * K + k0 + tx] = f2b(tile[tx][ty + i]);
}

// ---------------- GEMM: C = A[M,K] * B^T[N,K]^T + bias ----------------
// 128x128 tile, BK=64, 4 waves. Double-buffered LDS, counted vmcnt(8),
// (row&7)-XOR swizzled A/B tiles (linear LDS dest, pre-swizzled source).
// MODE 0: QKV epilogue -> Q (pre-scaled by 1/sqrt(D)*log2e), K as [B,H,T,D];
//         V as [B,H,D,T] (transposed). Writes re-staged through LDS, 16B
//         coalesced stores. MODE 1: proj epilogue -> f32 natural [M,N].

template <int MODE>
__global__ void __launch_bounds__(256) gemm_bt(
    const unsigned short* __restrict__ A, const unsigned short* __restrict__ Bt,
    const float* __restrict__ bias,
    unsigned short* __restrict__ Oq, unsigned short* __restrict__ Ok,
    unsigned short* __restrict__ Ov, float* __restrict__ Of,
    int M, int N, int K) {
  __shared__ unsigned short smem[4 * 128 * 64];  // 64 KB: As dbuf | Bs dbuf
  unsigned short* As = smem;
  unsigned short* Bs = smem + 2 * 128 * 64;

  const int tid = threadIdx.x;
  const int lane = tid & 63;
  const int wid = tid >> 6;
  const int wr = wid >> 1, wc = wid & 1;
  const int lr = lane & 15, lg = lane >> 4;
  const int m0 = blockIdx.x * 128;
  const int n0 = blockIdx.y * 128;

  f32x4 acc[4][4];
#pragma unroll
  for (int mi = 0; mi < 4; mi++)
#pragma unroll
    for (int ni = 0; ni < 4; ni++) acc[mi][ni] = (f32x4){0.f, 0.f, 0.f, 0.f};

  auto stage = [&](int t, int buf) {
    const int k0 = t * 64;
    unsigned short* Ad = As + buf * (128 * 64);
    unsigned short* Bd = Bs + buf * (128 * 64);
#pragma unroll
    for (int it = 0; it < 4; ++it) {
      const int chunk_u = it * 256 + (tid & ~63);  // wave-uniform 16B-chunk base
      const int chunk = chunk_u + lane;
      const int row = chunk >> 3;
      const int col = ((chunk & 7) ^ (row & 7)) * 8;  // pre-swizzled src col
      __builtin_amdgcn_global_load_lds(
          (GAS unsigned int*)(A + (size_t)(m0 + row) * K + k0 + col),
          (LAS unsigned int*)(Ad + chunk_u * 8), 16, 0, 0);
      __builtin_amdgcn_global_load_lds(
          (GAS unsigned int*)(Bt + (size_t)(n0 + row) * K + k0 + col),
          (LAS unsigned int*)(Bd + chunk_u * 8), 16, 0, 0);
    }
  };

  const int swa = (lr & 7) * 8;  // read-side XOR (row&7 == lr&7 for our rows)
  const int kt = K >> 6;

  stage(0, 0);

  for (int t = 0; t < kt; ++t) {
    const int cur = t & 1;
    __builtin_amdgcn_s_barrier();        // A: everyone done reading buf cur^1
    if (t + 1 < kt) {
      stage(t + 1, cur ^ 1);             // prefetch stays in flight (T4)
      asm volatile("s_waitcnt vmcnt(8)" ::: "memory");  // tile-t loads done
    } else {
      asm volatile("s_waitcnt vmcnt(0)" ::: "memory");
    }
    __builtin_amdgcn_s_barrier();        // B: tile t visible to all waves

    const unsigned short* Ab = As + cur * (128 * 64);
    const unsigned short* Bb = Bs + cur * (128 * 64);

#pragma unroll
    for (int kk = 0; kk < 2; ++kk) {
      bf16x8 af[4], bfr[4];
#pragma unroll
      for (int mi = 0; mi < 4; mi++)
        af[mi] = *(const bf16x8*)(Ab + (wr * 64 + mi * 16 + lr) * 64 +
                                  ((kk * 32 + lg * 8) ^ swa));
#pragma unroll
      for (int ni = 0; ni < 4; ni++)
        bfr[ni] = *(const bf16x8*)(Bb + (wc * 64 + ni * 16 + lr) * 64 +
                                   ((kk * 32 + lg * 8) ^ swa));
      __builtin_amdgcn_s_setprio(1);
#pragma unroll
      for (int mi = 0; mi < 4; mi++)
#pragma unroll
        for (int ni = 0; ni < 4; ni++)
          acc[mi][ni] = __builtin_amdgcn_mfma_f32_16x16x32_bf16(
              af[mi], bfr[ni], acc[mi][ni], 0, 0, 0);
      __builtin_amdgcn_s_setprio(0);
    }
  }

  const float SCLQ = 0.125f * 1.44269504088896340736f;  // 1/sqrt(64)*log2(e)

  if constexpr (MODE == 1) {
#pragma unroll
    for (int mi = 0; mi < 4; mi++) {
#pragma unroll
      for (int ni = 0; ni < 4; ni++) {
        const int nn = n0 + wc * 64 + ni * 16 + lr;
        const float bv = bias[nn];
#pragma unroll
        for (int r = 0; r < 4; r++) {
          const int mm = m0 + wr * 64 + mi * 16 + lg * 4 + r;
          Of[(size_t)mm * N + nn] = acc[mi][ni][r] + bv;
        }
      }
    }
  } else {
    // QKV epilogue: re-stage through LDS (reuse smem), write coalesced.
    unsigned short* L = smem;            // [128][136] bf16 (pad breaks banks)
    const int which = n0 >> 10;          // block-uniform third (0=Q,1=K,2=V)
    const float sc = (which == 0) ? SCLQ : 1.0f;
    __syncthreads();                     // all waves done reading As/Bs
#pragma unroll
    for (int mi = 0; mi < 4; mi++) {
#pragma unroll
      for (int ni = 0; ni < 4; ni++) {
        const int nn_l = wc * 64 + ni * 16 + lr;
        const float bv = bias[n0 + nn_l];
#pragma unroll
        for (int r = 0; r < 4; r++) {
          const int mm_l = wr * 64 + mi * 16 + lg * 4 + r;
          const unsigned short v = f2b((acc[mi][ni][r] + bv) * sc);
          if (which == 2) L[nn_l * 136 + mm_l] = v;   // V: store transposed
          else            L[mm_l * 136 + nn_l] = v;   // Q,K: natural
        }
      }
    }
    __syncthreads();
    const int b = m0 >> 11;
    const int t0 = m0 & 2047;
    const int h0 = (n0 & 1023) >> 6;
    if (which == 2) {
      const int row = tid >> 1;          // (hsub,d): 2 heads x 64 d
      const int hsub = row >> 6, d = row & 63;
      const int tt0 = (tid & 1) * 64;
      const unsigned short* src = L + row * 136 + tt0;
      unsigned short* dst = Ov +
          ((size_t)((b * 16 + h0 + hsub) * 64 + d)) * 2048 + t0 + tt0;
#pragma unroll
      for (int j = 0; j < 8; j++)
        *(u16x8*)(dst + j * 8) = *(const u16x8*)(src + j * 8);
    } else {
      const int mm_l = tid & 127;
      const int hsub = tid >> 7;
      const unsigned short* src = L + mm_l * 136 + hsub * 64;
      unsigned short* base = (which == 0) ? Oq : Ok;
      unsigned short* dst = base +
          ((size_t)(b * 16 + h0 + hsub) * 2048 + t0 + mm_l) * 64;
#pragma unroll
      for (int j = 0; j < 8; j++)
        *(u16x8*)(dst + j * 8) = *(const u16x8*)(src + j * 8);
    }
  }
}

// ---------------- flash attention (causal, KV-split) ----------------
// 896 blocks = 28 classes x 32 (b,h); 512 threads (8 waves x 16 q-rows).
// qt>=4: class is L half (KV tiles [0,qt+1), mask-free) or R half
// ([qt+1,2qt+2), has diagonal), writing unnormalized partials.
// qt<=3: unsplit (U), writes yatt directly. Classes sorted descending by
// size so HW round-robin balances per-CU work. K [64t][64d] and V^T
// [64d][64t] staged via global_load_lds + XOR swizzle, dbuf, counted
// vmcnt(2). Log2-domain softmax, scale pre-folded in Q, lane-local
// defer-max, row-sum via MFMA(P,ones), setprio on MFMA clusters.

__global__ void __launch_bounds__(512) attn_kernel(
    const unsigned short* __restrict__ Qh, const unsigned short* __restrict__ Kh,
    const unsigned short* __restrict__ Vh, unsigned short* __restrict__ yatt,
    unsigned short* __restrict__ Opart, float* __restrict__ Mp,
    float* __restrict__ Lp) {
  __shared__ unsigned short KsL[2 * 64 * 64];
  __shared__ unsigned short VsL[2 * 64 * 64];
  __shared__ unsigned short Pl[8 * 16 * 72];

  const int tid = threadIdx.x;
  const int lane = tid & 63;
  const int w = tid >> 6;                 // 0..7
  const int lr = lane & 15, lg = lane >> 4;

  const int cls = blockIdx.x >> 5;        // 0..27, sorted desc by work
  const int bh = blockIdx.x & 31;
  const int hh = bh & 15;
  const int bb = bh >> 4;

  // class tables packed as nibbles / 2-bit fields (no runtime-indexed array)
  const unsigned long long QA = 0x8899AABBCCDDEEFFull;   // qt for cls 0..15
  const unsigned long long QB = 0x0000014425566377ull;   // qt for cls 16..27
  const unsigned long long KK = 0x00A4912444444444ull;   // kind 2b: 0=L,1=R,2=U
  const int qt = (cls < 16) ? (int)((QA >> (4 * cls)) & 15)
                            : (int)((QB >> (4 * (cls - 16))) & 15);
  const int kind = (int)((KK >> (2 * cls)) & 3);
  const int t0 = (kind == 1) ? (qt + 1) : 0;
  const int t1 = (kind == 0) ? (qt + 1) : (2 * qt + 2);

  const size_t head_base = ((size_t)(bb * 16 + hh)) * 2048 * 64;
  const unsigned short* Qg = Qh + head_base;
  const unsigned short* Kg = Kh + head_base;
  const unsigned short* Vg = Vh + head_base;  // [D=64][T=2048] within head

  const int q0 = qt * 128 + w * 16;
  const int diagw = 2 * qt + ((w >> 2) & 1);  // wave's diagonal KV-tile index

  bf16x8 aq0 = *(const bf16x8*)(Qg + (size_t)(q0 + lr) * 64 + lg * 8);
  bf16x8 aq1 = *(const bf16x8*)(Qg + (size_t)(q0 + lr) * 64 + 32 + lg * 8);

  bf16x8 vones;
#pragma unroll
  for (int j = 0; j < 8; j++) vones[j] = (__bf16)1.0f;

  float m_run[4], l_run[4];
  f32x4 acc_o[4];
#pragma unroll
  for (int r = 0; r < 4; r++) { m_run[r] = -__builtin_inff(); l_run[r] = 0.f; }
#pragma unroll
  for (int dj = 0; dj < 4; dj++) acc_o[dj] = (f32x4){0.f, 0.f, 0.f, 0.f};

  // staging: 512 threads x 1 chunk each per array (row = tid>>3)
  const int srow = tid >> 3;
  const int scol = (((tid & 7) ^ (srow & 7)) << 3);  // pre-swizzled src col

  auto stage = [&](int kv0, int buf) {
    unsigned short* Kd = KsL + buf * (64 * 64);
    unsigned short* Vd = VsL + buf * (64 * 64);
    const int base_u = (tid & ~63) * 8;   // wave-uniform LDS chunk base
    __builtin_amdgcn_global_load_lds(
        (GAS unsigned int*)(Kg + (size_t)(kv0 + srow) * 64 + scol),
        (LAS unsigned int*)(Kd + base_u), 16, 0, 0);
    __builtin_amdgcn_global_load_lds(
        (GAS unsigned int*)(Vg + (size_t)srow * 2048 + kv0 + scol),
        (LAS unsigned int*)(Vd + base_u), 16, 0, 0);
  };

  __bf16* Pw = (__bf16*)(Pl + w * 16 * 72);
  const int swr = (lr & 7) << 3;  // read-side XOR for row (nj*16+lr)

  stage(t0 * 64, t0 & 1);

  for (int i = t0; i < t1; ++i) {
    const int cur = i & 1;
    __builtin_amdgcn_s_barrier();        // A: protect buf cur^1
    if (i + 1 < t1) {
      stage((i + 1) * 64, cur ^ 1);      // prefetch stays in flight (T4)
      asm volatile("s_waitcnt vmcnt(2)" ::: "memory");  // tile-i loads done
    } else {
      asm volatile("s_waitcnt vmcnt(0)" ::: "memory");
    }
    __builtin_amdgcn_s_barrier();        // B: tile i visible

    if (i <= diagw) {                    // wave-uniform: skip masked tiles
      const int kv0 = i * 64;
      const unsigned short* Kb = KsL + cur * (64 * 64);
      const unsigned short* Vb = VsL + cur * (64 * 64);

      // QK^T (pre-scaled, log2 domain): S[16 q rows][64 keys]
      f32x4 s[4];
      __builtin_amdgcn_s_setprio(1);
#pragma unroll
      for (int nj = 0; nj < 4; nj++) {
        const unsigned short* krow = Kb + (nj * 16 + lr) * 64;
        bf16x8 kb0 = *(const bf16x8*)(krow + ((lg * 8) ^ swr));
        bf16x8 kb1 = *(const bf16x8*)(krow + ((32 + lg * 8) ^ swr));
        f32x4 z = (f32x4){0.f, 0.f, 0.f, 0.f};
        z = __builtin_amdgcn_mfma_f32_16x16x32_bf16(aq0, kb0, z, 0, 0, 0);
        z = __builtin_amdgcn_mfma_f32_16x16x32_bf16(aq1, kb1, z, 0, 0, 0);
        s[nj] = z;
      }
      __builtin_amdgcn_s_setprio(0);

      // causal mask only on the wave's diagonal tile
      if (i == diagw) {
#pragma unroll
        for (int nj = 0; nj < 4; nj++) {
          const int key = kv0 + nj * 16 + lr;
#pragma unroll
          for (int r = 0; r < 4; r++) {
            const int qrow = q0 + lg * 4 + r;
            if (key > qrow) s[nj][r] = -__builtin_inff();
          }
        }
      }

      // lane-local per-row max
      float pm[4];
#pragma unroll
      for (int r = 0; r < 4; r++)
        pm[r] = fmaxf(fmaxf(s[0][r], s[1][r]), fmaxf(s[2][r], s[3][r]));

      // defer-max (T13, THR=8)
      const bool okl = (pm[0] <= m_run[0] + 8.f) & (pm[1] <= m_run[1] + 8.f) &
                       (pm[2] <= m_run[2] + 8.f) & (pm[3] <= m_run[3] + 8.f);
      if (!__all(okl)) {
#pragma unroll
        for (int r = 0; r < 4; r++) {
#pragma unroll
          for (int off = 1; off < 16; off <<= 1)
            pm[r] = fmaxf(pm[r], __shfl_xor(pm[r], off));
          const float mn = fmaxf(m_run[r], pm[r]);
          const float sc = exp2f(m_run[r] - mn);
          m_run[r] = mn;
          l_run[r] *= sc;
#pragma unroll
          for (int dj = 0; dj < 4; dj++) acc_o[dj][r] *= sc;
        }
      }

      // P = exp2(s - m) -> bf16 -> LDS
#pragma unroll
      for (int nj = 0; nj < 4; nj++) {
#pragma unroll
        for (int r = 0; r < 4; r++) {
          const float p = exp2f(s[nj][r] - m_run[r]);
          Pw[(lg * 4 + r) * 72 + nj * 16 + lr] = (__bf16)p;
        }
      }

      bf16x8 pa0 = *(const bf16x8*)(Pw + lr * 72 + lg * 8);
      bf16x8 pa1 = *(const bf16x8*)(Pw + lr * 72 + 32 + lg * 8);

      __builtin_amdgcn_s_setprio(1);
      // row sums via MFMA(P, ones)
      f32x4 zs = (f32x4){0.f, 0.f, 0.f, 0.f};
      zs = __builtin_amdgcn_mfma_f32_16x16x32_bf16(pa0, vones, zs, 0, 0, 0);
      zs = __builtin_amdgcn_mfma_f32_16x16x32_bf16(pa1, vones, zs, 0, 0, 0);

      // PV: O += P[16,64] * V^T[64 d][64 t]
#pragma unroll
      for (int dj = 0; dj < 4; dj++) {
        const unsigned short* vrow = Vb + (dj * 16 + lr) * 64;
        bf16x8 vb0 = *(const bf16x8*)(vrow + ((lg * 8) ^ swr));
        bf16x8 vb1 = *(const bf16x8*)(vrow + ((32 + lg * 8) ^ swr));
        acc_o[dj] = __builtin_amdgcn_mfma_f32_16x16x32_bf16(pa0, vb0, acc_o[dj], 0, 0, 0);
        acc_o[dj] = __builtin_amdgcn_mfma_f32_16x16x32_bf16(pa1, vb1, acc_o[dj], 0, 0, 0);
      }
      __builtin_amdgcn_s_setprio(0);

#pragma unroll
      for (int r = 0; r < 4; r++) l_run[r] += zs[r];
    }
  }

  if (kind == 2) {
    // unsplit: normalize, write bf16 [B,T,C] (heads re-merged)
    __bf16* yb = (__bf16*)yatt;
#pragma unroll
    for (int r = 0; r < 4; r++) {
      const float inv = 1.0f / l_run[r];
      const int t = q0 + lg * 4 + r;
      const size_t rowbase = ((size_t)(bb * 2048 + t)) * 1024 + hh * 64;
#pragma unroll
      for (int dj = 0; dj < 4; dj++)
        yb[rowbase + dj * 16 + lr] = (__bf16)(acc_o[dj][r] * inv);
    }
  } else {
    // split half: write unnormalized partial O (bf16) + m,l (f32)
    __bf16* Ob = (__bf16*)Opart;
#pragma unroll
    for (int r = 0; r < 4; r++) {
      const int slot = bh * 1536 + (q0 + lg * 4 + r) - 512;
      const size_t obase = ((size_t)(kind * 49152 + slot)) * 64;
#pragma unroll
      for (int dj = 0; dj < 4; dj++)
        Ob[obase + dj * 16 + lr] = (__bf16)acc_o[dj][r];
      if (lr == 0) {
        Mp[kind * 49152 + slot] = m_run[r];
        Lp[kind * 49152 + slot] = l_run[r];
      }
    }
  }
}

// combine L/R partials: y = (O1*2^(m1-m) + O2*2^(m2-m)) / (l1*2^(m1-m)+l2*2^(m2-m))
__global__ void __launch_bounds__(256) attn_merge(
    const unsigned short* __restrict__ Op, const float* __restrict__ Mp,
    const float* __restrict__ Lp, unsigned short* __restrict__ yatt) {
  const int gid = blockIdx.x * 256 + threadIdx.x;  // 48*256 = 12288 per bh
  const int sl = gid >> 3;                         // 0..1535
  const int d0 = (gid & 7) * 8;
  const int bh = blockIdx.y;
  const int slot = bh * 1536 + sl;
  const float m1 = Mp[slot], m2 = Mp[49152 + slot];
  const float l1 = Lp[slot], l2 = Lp[49152 + slot];
  const float mx = fmaxf(m1, m2);
  const float w1 = exp2f(m1 - mx), w2 = exp2f(m2 - mx);
  const float inv = 1.0f / (l1 * w1 + l2 * w2);
  u16x8 a = *(const u16x8*)(Op + (size_t)slot * 64 + d0);
  u16x8 b = *(const u16x8*)(Op + (size_t)(49152 + slot) * 64 + d0);
  const int qr = 512 + sl;
  unsigned short* dst = yatt +
      ((size_t)((bh >> 4) * 2048 + qr)) * 1024 + (bh & 15) * 64 + d0;
  u16x8 o;
#pragma unroll
  for (int j = 0; j < 8; j++)
    o[j] = f2b((b2f(a[j]) * w1 + b2f(b[j]) * w2) * inv);
  *(u16x8*)dst = o;
}

// ---------------- launcher ----------------

extern "C" void kernel_launch(void* const* d_in, const int* in_sizes, int n_in,
                              void* d_out, int out_size, void* d_ws,
                              size_t ws_size, hipStream_t stream) {
  (void)in_sizes; (void)n_in; (void)out_size; (void)ws_size;
  const float* x      = (const float*)d_in[0];  // [2,2048,1024]
  const float* w_qkv  = (const float*)d_in[1];  // [1024,3072]
  const float* b_qkv  = (const float*)d_in[2];  // [3072]
  const float* w_proj = (const float*)d_in[3];  // [1024,1024]
  const float* b_proj = (const float*)d_in[4];  // [1024]
  float* out = (float*)d_out;                   // [2,2048,1024] f32

  unsigned short* ws     = (unsigned short*)d_ws;
  unsigned short* xb     = ws;                                  // 4096*1024
  unsigned short* wqkvT  = xb     + (size_t)4096 * 1024;        // 3072*1024
  unsigned short* wprojT = wqkvT  + (size_t)3072 * 1024;        // 1024*1024
  unsigned short* Qh     = wprojT + (size_t)1024 * 1024;        // 2*16*2048*64
  unsigned short* Kh     = Qh     + (size_t)2 * 16 * 2048 * 64;
  unsigned short* Vh     = Kh     + (size_t)2 * 16 * 2048 * 64; // [B,H,D,T]
  unsigned short* yatt   = Vh     + (size_t)2 * 16 * 2048 * 64; // 4096*1024

  // attn partials alias xb/wqkvT (dead after QKV GEMM); wprojT untouched.
  unsigned short* Opart = ws;                      // [2][49152][64] bf16
  float* Mp = (float*)(ws + (size_t)6291456);      // [2][49152] f32
  float* Lp = Mp + 2 * 49152;                      // [2][49152] f32

  cvt_f32_to_bf16<<<4096, 256, 0, stream>>>(x, xb, 1048576);
  transpose_f32_to_bf16<<<dim3(96, 32), dim3(32, 8), 0, stream>>>(w_qkv, wqkvT, 1024, 3072);
  transpose_f32_to_bf16<<<dim3(32, 32), dim3(32, 8), 0, stream>>>(w_proj, wprojT, 1024, 1024);

  gemm_bt<0><<<dim3(32, 24), 256, 0, stream>>>(xb, wqkvT, b_qkv, Qh, Kh, Vh,
                                               nullptr, 4096, 3072, 1024);
  attn_kernel<<<896, 512, 0, stream>>>(Qh, Kh, Vh, yatt, Opart, Mp, Lp);
  attn_merge<<<dim3(48, 32), 256, 0, stream>>>(Opart, Mp, Lp, yatt);
  gemm_bt<1><<<dim3(32, 8), 256, 0, stream>>>(yatt, wprojT, b_proj, nullptr,
                                              nullptr, nullptr, out, 4096, 1024, 1024);
}

// Round 8
// 117.920 us; speedup vs baseline: 2.3009x; 1.0275x over previous
//
#include <hip/hip_runtime.h>

// ---------------------------------------------------------------------------
// CausalSelfAttention: x@Wqkv -> split heads -> causal flash attn -> @Wproj
// B=2 T=2048 C=1024 H=16 D=64. All matmuls bf16 MFMA (16x16x32), f32 accum.
// Round 8: attn LDS-pipe diet — 4 waves x 32 q-rows (same QBLK=128 grid /
// classes / split / merge as round 7), swapped QK^T (mfma(K,Q)) so each lane
// owns one q-row: P packed as 4x ds_write_b64 (was 16x b16), scalar m/l per
// lane, l-reduce deferred to epilogue. K/V tile reads amortized over 2x rows.
// ---------------------------------------------------------------------------

typedef __attribute__((ext_vector_type(8))) __bf16 bf16x8;
typedef __attribute__((ext_vector_type(4))) __bf16 bf16x4;
typedef __attribute__((ext_vector_type(4))) float f32x4;
typedef __attribute__((ext_vector_type(8))) unsigned short u16x8;
typedef __attribute__((ext_vector_type(4))) unsigned short u16x4;

#define GAS __attribute__((address_space(1)))
#define LAS __attribute__((address_space(3)))

__device__ __forceinline__ unsigned short f2b(float f) {
  unsigned int u = __float_as_uint(f);
  unsigned int r = 0x7FFFu + ((u >> 16) & 1u);
  return (unsigned short)((u + r) >> 16);
}
__device__ __forceinline__ float b2f(unsigned short u) {
  return __uint_as_float((unsigned int)u << 16);
}

// ---------------- prep kernels ----------------

__global__ void cvt_f32_to_bf16(const float* __restrict__ src,
                                unsigned short* __restrict__ dst, int n4) {
  int i = blockIdx.x * blockDim.x + threadIdx.x;
  if (i < n4) {
    float4 v = ((const float4*)src)[i];
    u16x4 o = { f2b(v.x), f2b(v.y), f2b(v.z), f2b(v.w) };
    *(u16x4*)(dst + (size_t)i * 4) = o;
  }
}

// src [K][N] f32  ->  dst [N][K] bf16
__global__ void transpose_f32_to_bf16(const float* __restrict__ src,
                                      unsigned short* __restrict__ dst,
                                      int K, int N) {
  __shared__ float tile[32][33];
  int n0 = blockIdx.x * 32, k0 = blockIdx.y * 32;
  int tx = threadIdx.x, ty = threadIdx.y;  // 32 x 8
#pragma unroll
  for (int i = 0; i < 32; i += 8)
    tile[ty + i][tx] = src[(size_t)(k0 + ty + i) * N + n0 + tx];
  __syncthreads();
#pragma unroll
  for (int i = 0; i < 32; i += 8)
    dst[(size_t)(n0 + ty + i) * K + k0 + tx] = f2b(tile[tx][ty + i]);
}

// ---------------- GEMM: C = A[M,K] * B^T[N,K]^T + bias ----------------
// 128x128 tile, BK=64, 4 waves. Double-buffered LDS, counted vmcnt(8),
// (row&7)-XOR swizzled A/B tiles (linear LDS dest, pre-swizzled source).
// MODE 0: QKV epilogue -> Q (pre-scaled by 1/sqrt(D)*log2e), K as [B,H,T,D];
//         V as [B,H,D,T] (transposed). Writes re-staged through LDS, 16B
//         coalesced stores. MODE 1: proj epilogue -> f32 natural [M,N].

template <int MODE>
__global__ void __launch_bounds__(256) gemm_bt(
    const unsigned short* __restrict__ A, const unsigned short* __restrict__ Bt,
    const float* __restrict__ bias,
    unsigned short* __restrict__ Oq, unsigned short* __restrict__ Ok,
    unsigned short* __restrict__ Ov, float* __restrict__ Of,
    int M, int N, int K) {
  __shared__ unsigned short smem[4 * 128 * 64];  // 64 KB: As dbuf | Bs dbuf
  unsigned short* As = smem;
  unsigned short* Bs = smem + 2 * 128 * 64;

  const int tid = threadIdx.x;
  const int lane = tid & 63;
  const int wid = tid >> 6;
  const int wr = wid >> 1, wc = wid & 1;
  const int lr = lane & 15, lg = lane >> 4;
  const int m0 = blockIdx.x * 128;
  const int n0 = blockIdx.y * 128;

  f32x4 acc[4][4];
#pragma unroll
  for (int mi = 0; mi < 4; mi++)
#pragma unroll
    for (int ni = 0; ni < 4; ni++) acc[mi][ni] = (f32x4){0.f, 0.f, 0.f, 0.f};

  auto stage = [&](int t, int buf) {
    const int k0 = t * 64;
    unsigned short* Ad = As + buf * (128 * 64);
    unsigned short* Bd = Bs + buf * (128 * 64);
#pragma unroll
    for (int it = 0; it < 4; ++it) {
      const int chunk_u = it * 256 + (tid & ~63);  // wave-uniform 16B-chunk base
      const int chunk = chunk_u + lane;
      const int row = chunk >> 3;
      const int col = ((chunk & 7) ^ (row & 7)) * 8;  // pre-swizzled src col
      __builtin_amdgcn_global_load_lds(
          (GAS unsigned int*)(A + (size_t)(m0 + row) * K + k0 + col),
          (LAS unsigned int*)(Ad + chunk_u * 8), 16, 0, 0);
      __builtin_amdgcn_global_load_lds(
          (GAS unsigned int*)(Bt + (size_t)(n0 + row) * K + k0 + col),
          (LAS unsigned int*)(Bd + chunk_u * 8), 16, 0, 0);
    }
  };

  const int swa = (lr & 7) * 8;  // read-side XOR (row&7 == lr&7 for our rows)
  const int kt = K >> 6;

  stage(0, 0);

  for (int t = 0; t < kt; ++t) {
    const int cur = t & 1;
    __builtin_amdgcn_s_barrier();        // A: everyone done reading buf cur^1
    if (t + 1 < kt) {
      stage(t + 1, cur ^ 1);             // prefetch stays in flight (T4)
      asm volatile("s_waitcnt vmcnt(8)" ::: "memory");  // tile-t loads done
    } else {
      asm volatile("s_waitcnt vmcnt(0)" ::: "memory");
    }
    __builtin_amdgcn_s_barrier();        // B: tile t visible to all waves

    const unsigned short* Ab = As + cur * (128 * 64);
    const unsigned short* Bb = Bs + cur * (128 * 64);

#pragma unroll
    for (int kk = 0; kk < 2; ++kk) {
      bf16x8 af[4], bfr[4];
#pragma unroll
      for (int mi = 0; mi < 4; mi++)
        af[mi] = *(const bf16x8*)(Ab + (wr * 64 + mi * 16 + lr) * 64 +
                                  ((kk * 32 + lg * 8) ^ swa));
#pragma unroll
      for (int ni = 0; ni < 4; ni++)
        bfr[ni] = *(const bf16x8*)(Bb + (wc * 64 + ni * 16 + lr) * 64 +
                                   ((kk * 32 + lg * 8) ^ swa));
      __builtin_amdgcn_s_setprio(1);
#pragma unroll
      for (int mi = 0; mi < 4; mi++)
#pragma unroll
        for (int ni = 0; ni < 4; ni++)
          acc[mi][ni] = __builtin_amdgcn_mfma_f32_16x16x32_bf16(
              af[mi], bfr[ni], acc[mi][ni], 0, 0, 0);
      __builtin_amdgcn_s_setprio(0);
    }
  }

  const float SCLQ = 0.125f * 1.44269504088896340736f;  // 1/sqrt(64)*log2(e)

  if constexpr (MODE == 1) {
#pragma unroll
    for (int mi = 0; mi < 4; mi++) {
#pragma unroll
      for (int ni = 0; ni < 4; ni++) {
        const int nn = n0 + wc * 64 + ni * 16 + lr;
        const float bv = bias[nn];
#pragma unroll
        for (int r = 0; r < 4; r++) {
          const int mm = m0 + wr * 64 + mi * 16 + lg * 4 + r;
          Of[(size_t)mm * N + nn] = acc[mi][ni][r] + bv;
        }
      }
    }
  } else {
    // QKV epilogue: re-stage through LDS (reuse smem), write coalesced.
    unsigned short* L = smem;            // [128][136] bf16 (pad breaks banks)
    const int which = n0 >> 10;          // block-uniform third (0=Q,1=K,2=V)
    const float sc = (which == 0) ? SCLQ : 1.0f;
    __syncthreads();                     // all waves done reading As/Bs
#pragma unroll
    for (int mi = 0; mi < 4; mi++) {
#pragma unroll
      for (int ni = 0; ni < 4; ni++) {
        const int nn_l = wc * 64 + ni * 16 + lr;
        const float bv = bias[n0 + nn_l];
#pragma unroll
        for (int r = 0; r < 4; r++) {
          const int mm_l = wr * 64 + mi * 16 + lg * 4 + r;
          const unsigned short v = f2b((acc[mi][ni][r] + bv) * sc);
          if (which == 2) L[nn_l * 136 + mm_l] = v;   // V: store transposed
          else            L[mm_l * 136 + nn_l] = v;   // Q,K: natural
        }
      }
    }
    __syncthreads();
    const int b = m0 >> 11;
    const int t0 = m0 & 2047;
    const int h0 = (n0 & 1023) >> 6;
    if (which == 2) {
      const int row = tid >> 1;          // (hsub,d): 2 heads x 64 d
      const int hsub = row >> 6, d = row & 63;
      const int tt0 = (tid & 1) * 64;
      const unsigned short* src = L + row * 136 + tt0;
      unsigned short* dst = Ov +
          ((size_t)((b * 16 + h0 + hsub) * 64 + d)) * 2048 + t0 + tt0;
#pragma unroll
      for (int j = 0; j < 8; j++)
        *(u16x8*)(dst + j * 8) = *(const u16x8*)(src + j * 8);
    } else {
      const int mm_l = tid & 127;
      const int hsub = tid >> 7;
      const unsigned short* src = L + mm_l * 136 + hsub * 64;
      unsigned short* base = (which == 0) ? Oq : Ok;
      unsigned short* dst = base +
          ((size_t)(b * 16 + h0 + hsub) * 2048 + t0 + mm_l) * 64;
#pragma unroll
      for (int j = 0; j < 8; j++)
        *(u16x8*)(dst + j * 8) = *(const u16x8*)(src + j * 8);
    }
  }
}

// ---------------- flash attention (causal, KV-split) ----------------
// 896 blocks = 28 classes x 32 (b,h); 256 threads = 4 waves x 32 q-rows.
// Swapped QK^T: s = mfma(K, Q) puts qrow on lane (col=lr), keys on regs ->
// scalar m/l per lane, P packed as b64 writes, l-reduce deferred to epilogue.
// K [64t][64d] and V^T [64d][64t] staged via global_load_lds + XOR swizzle,
// dbuf, counted vmcnt(4). Classes/split/merge identical to round 7.

__global__ void __launch_bounds__(256, 3) attn_kernel(
    const unsigned short* __restrict__ Qh, const unsigned short* __restrict__ Kh,
    const unsigned short* __restrict__ Vh, unsigned short* __restrict__ yatt,
    unsigned short* __restrict__ Opart, float* __restrict__ Mp,
    float* __restrict__ Lp) {
  __shared__ unsigned short KsL[2 * 64 * 64];
  __shared__ unsigned short VsL[2 * 64 * 64];
  __shared__ unsigned short Pl[4 * 32 * 72];

  const int tid = threadIdx.x;
  const int lane = tid & 63;
  const int w = tid >> 6;                 // 0..3
  const int lr = lane & 15, lg = lane >> 4;

  const int cls = blockIdx.x >> 5;        // 0..27, sorted desc by work
  const int bh = blockIdx.x & 31;
  const int hh = bh & 15;
  const int bb = bh >> 4;

  // class tables packed as nibbles / 2-bit fields (no runtime-indexed array)
  const unsigned long long QA = 0x8899AABBCCDDEEFFull;   // qt for cls 0..15
  const unsigned long long QB = 0x0000014425566377ull;   // qt for cls 16..27
  const unsigned long long KK = 0x00A4912444444444ull;   // kind 2b: 0=L,1=R,2=U
  const int qt = (cls < 16) ? (int)((QA >> (4 * cls)) & 15)
                            : (int)((QB >> (4 * (cls - 16))) & 15);
  const int kind = (int)((KK >> (2 * cls)) & 3);
  const int t0 = (kind == 1) ? (qt + 1) : 0;
  const int t1 = (kind == 0) ? (qt + 1) : (2 * qt + 2);

  const size_t head_base = ((size_t)(bb * 16 + hh)) * 2048 * 64;
  const unsigned short* Qg = Qh + head_base;
  const unsigned short* Kg = Kh + head_base;
  const unsigned short* Vg = Vh + head_base;  // [D=64][T=2048] within head

  const int q0 = qt * 128 + w * 32;           // wave's first q-row (32 rows)
  const int diagw = 2 * qt + (w >> 1);        // wave's diagonal KV-tile index

  // Q fragments: half A rows q0+lr, half B rows q0+16+lr (B-operand layout)
  bf16x8 aqA0 = *(const bf16x8*)(Qg + (size_t)(q0 + lr) * 64 + lg * 8);
  bf16x8 aqA1 = *(const bf16x8*)(Qg + (size_t)(q0 + lr) * 64 + 32 + lg * 8);
  bf16x8 aqB0 = *(const bf16x8*)(Qg + (size_t)(q0 + 16 + lr) * 64 + lg * 8);
  bf16x8 aqB1 = *(const bf16x8*)(Qg + (size_t)(q0 + 16 + lr) * 64 + 32 + lg * 8);

  float mA = -__builtin_inff(), mB = -__builtin_inff();
  float lA = 0.f, lB = 0.f;                   // lane-local partial row sums
  f32x4 oA[4], oB[4];
#pragma unroll
  for (int dj = 0; dj < 4; dj++) {
    oA[dj] = (f32x4){0.f, 0.f, 0.f, 0.f};
    oB[dj] = (f32x4){0.f, 0.f, 0.f, 0.f};
  }

  // staging: 256 threads x 2 chunks each per array
  auto stage = [&](int kv0, int buf) {
    unsigned short* Kd = KsL + buf * (64 * 64);
    unsigned short* Vd = VsL + buf * (64 * 64);
#pragma unroll
    for (int it = 0; it < 2; ++it) {
      const int chunk_u = it * 256 + (tid & ~63);  // wave-uniform base
      const int chunk = chunk_u + lane;
      const int row = chunk >> 3;
      const int col = ((chunk & 7) ^ (row & 7)) << 3;  // pre-swizzled src col
      __builtin_amdgcn_global_load_lds(
          (GAS unsigned int*)(Kg + (size_t)(kv0 + row) * 64 + col),
          (LAS unsigned int*)(Kd + chunk_u * 8), 16, 0, 0);
      __builtin_amdgcn_global_load_lds(
          (GAS unsigned int*)(Vg + (size_t)row * 2048 + kv0 + col),
          (LAS unsigned int*)(Vd + chunk_u * 8), 16, 0, 0);
    }
  };

  __bf16* Pw = (__bf16*)(Pl + w * 32 * 72);
  const int swr = (lr & 7) << 3;  // read-side XOR for row (nj*16+lr)

  stage(t0 * 64, t0 & 1);

  for (int i = t0; i < t1; ++i) {
    const int cur = i & 1;
    __builtin_amdgcn_s_barrier();        // A: protect buf cur^1
    if (i + 1 < t1) {
      stage((i + 1) * 64, cur ^ 1);      // prefetch stays in flight (T4)
      asm volatile("s_waitcnt vmcnt(4)" ::: "memory");  // tile-i loads done
    } else {
      asm volatile("s_waitcnt vmcnt(0)" ::: "memory");
    }
    __builtin_amdgcn_s_barrier();        // B: tile i visible

    if (i <= diagw) {                    // wave-uniform: skip masked tiles
      const int kv0 = i * 64;
      const unsigned short* Kb = KsL + cur * (64 * 64);
      const unsigned short* Vb = VsL + cur * (64 * 64);

      // swapped QK^T: s = mfma(K, Q) -> col=lr=qrow, row=lg*4+r=key offset
      f32x4 sA[4], sB[4];
      __builtin_amdgcn_s_setprio(1);
#pragma unroll
      for (int nj = 0; nj < 4; nj++) {
        const unsigned short* krow = Kb + (nj * 16 + lr) * 64;
        bf16x8 kb0 = *(const bf16x8*)(krow + ((lg * 8) ^ swr));
        bf16x8 kb1 = *(const bf16x8*)(krow + ((32 + lg * 8) ^ swr));
        f32x4 zA = (f32x4){0.f, 0.f, 0.f, 0.f};
        f32x4 zB = (f32x4){0.f, 0.f, 0.f, 0.f};
        zA = __builtin_amdgcn_mfma_f32_16x16x32_bf16(kb0, aqA0, zA, 0, 0, 0);
        zA = __builtin_amdgcn_mfma_f32_16x16x32_bf16(kb1, aqA1, zA, 0, 0, 0);
        zB = __builtin_amdgcn_mfma_f32_16x16x32_bf16(kb0, aqB0, zB, 0, 0, 0);
        zB = __builtin_amdgcn_mfma_f32_16x16x32_bf16(kb1, aqB1, zB, 0, 0, 0);
        sA[nj] = zA;
        sB[nj] = zB;
      }
      __builtin_amdgcn_s_setprio(0);

      // causal mask only on the wave's diagonal tile
      if (i == diagw) {
        const int qrA = q0 + lr, qrB = q0 + 16 + lr;
#pragma unroll
        for (int nj = 0; nj < 4; nj++) {
#pragma unroll
          for (int r = 0; r < 4; r++) {
            const int key = kv0 + nj * 16 + lg * 4 + r;
            if (key > qrA) sA[nj][r] = -__builtin_inff();
            if (key > qrB) sB[nj][r] = -__builtin_inff();
          }
        }
      }

      // lane-local per-row max (lane owns 16 of row's 64 keys)
      float pmA = sA[0][0], pmB = sB[0][0];
#pragma unroll
      for (int nj = 0; nj < 4; nj++)
#pragma unroll
        for (int r = 0; r < 4; r++) {
          pmA = fmaxf(pmA, sA[nj][r]);
          pmB = fmaxf(pmB, sB[nj][r]);
        }

      // defer-max (T13, THR=8): row max <= m+8 iff all 4 owner lanes agree
      const bool okl = (pmA <= mA + 8.f) & (pmB <= mB + 8.f);
      if (!__all(okl)) {                 // rare: first tile + rare growth
        // full row max across the 4 owner lanes (xor 16, 32)
        pmA = fmaxf(pmA, __shfl_xor(pmA, 16));
        pmA = fmaxf(pmA, __shfl_xor(pmA, 32));
        pmB = fmaxf(pmB, __shfl_xor(pmB, 16));
        pmB = fmaxf(pmB, __shfl_xor(pmB, 32));
        const float mnA = fmaxf(mA, pmA), mnB = fmaxf(mB, pmB);
        const float scA = exp2f(mA - mnA), scB = exp2f(mB - mnB);
        mA = mnA; mB = mnB;
        lA *= scA; lB *= scB;
#pragma unroll
        for (int r = 0; r < 4; r++) {
          const float cA = __shfl(scA, lg * 4 + r);  // sc of row lg*4+r
          const float cB = __shfl(scB, lg * 4 + r);
#pragma unroll
          for (int dj = 0; dj < 4; dj++) {
            oA[dj][r] *= cA;
            oB[dj][r] *= cB;
          }
        }
      }

      // P = exp2(s - m) -> bf16x4 packed writes (keys contiguous per lane)
#pragma unroll
      for (int nj = 0; nj < 4; nj++) {
        const float a0 = exp2f(sA[nj][0] - mA), a1 = exp2f(sA[nj][1] - mA);
        const float a2 = exp2f(sA[nj][2] - mA), a3 = exp2f(sA[nj][3] - mA);
        lA += (a0 + a1) + (a2 + a3);
        bf16x4 pkA = {(__bf16)a0, (__bf16)a1, (__bf16)a2, (__bf16)a3};
        *(bf16x4*)(Pw + lr * 72 + nj * 16 + lg * 4) = pkA;
        const float b0 = exp2f(sB[nj][0] - mB), b1 = exp2f(sB[nj][1] - mB);
        const float b2 = exp2f(sB[nj][2] - mB), b3 = exp2f(sB[nj][3] - mB);
        lB += (b0 + b1) + (b2 + b3);
        bf16x4 pkB = {(__bf16)b0, (__bf16)b1, (__bf16)b2, (__bf16)b3};
        *(bf16x4*)(Pw + (16 + lr) * 72 + nj * 16 + lg * 4) = pkB;
      }

      // PV A-fragments (DS ops in-order within wave; no barrier needed)
      bf16x8 paA0 = *(const bf16x8*)(Pw + lr * 72 + lg * 8);
      bf16x8 paA1 = *(const bf16x8*)(Pw + lr * 72 + 32 + lg * 8);
      bf16x8 paB0 = *(const bf16x8*)(Pw + (16 + lr) * 72 + lg * 8);
      bf16x8 paB1 = *(const bf16x8*)(Pw + (16 + lr) * 72 + 32 + lg * 8);

      // PV: O += P[32,64] * V^T (vb shared across halves)
      __builtin_amdgcn_s_setprio(1);
#pragma unroll
      for (int dj = 0; dj < 4; dj++) {
        const unsigned short* vrow = Vb + (dj * 16 + lr) * 64;
        bf16x8 vb0 = *(const bf16x8*)(vrow + ((lg * 8) ^ swr));
        bf16x8 vb1 = *(const bf16x8*)(vrow + ((32 + lg * 8) ^ swr));
        oA[dj] = __builtin_amdgcn_mfma_f32_16x16x32_bf16(paA0, vb0, oA[dj], 0, 0, 0);
        oA[dj] = __builtin_amdgcn_mfma_f32_16x16x32_bf16(paA1, vb1, oA[dj], 0, 0, 0);
        oB[dj] = __builtin_amdgcn_mfma_f32_16x16x32_bf16(paB0, vb0, oB[dj], 0, 0, 0);
        oB[dj] = __builtin_amdgcn_mfma_f32_16x16x32_bf16(paB1, vb1, oB[dj], 0, 0, 0);
      }
      __builtin_amdgcn_s_setprio(0);
    }
  }

  // finalize l: full row sums (partials live on the 4 owner lanes)
  lA += __shfl_xor(lA, 16); lA += __shfl_xor(lA, 32);
  lB += __shfl_xor(lB, 16); lB += __shfl_xor(lB, 32);

  if (kind == 2) {
    // unsplit: normalize, write bf16 [B,T,C] (heads re-merged)
    __bf16* yb = (__bf16*)yatt;
#pragma unroll
    for (int r = 0; r < 4; r++) {
      const float invA = 1.0f / __shfl(lA, lg * 4 + r);
      const float invB = 1.0f / __shfl(lB, lg * 4 + r);
      const int tA = q0 + lg * 4 + r;
      const int tB = tA + 16;
      const size_t baseA = ((size_t)(bb * 2048 + tA)) * 1024 + hh * 64;
      const size_t baseB = ((size_t)(bb * 2048 + tB)) * 1024 + hh * 64;
#pragma unroll
      for (int dj = 0; dj < 4; dj++) {
        yb[baseA + dj * 16 + lr] = (__bf16)(oA[dj][r] * invA);
        yb[baseB + dj * 16 + lr] = (__bf16)(oB[dj][r] * invB);
      }
    }
  } else {
    // split half: write unnormalized partial O (bf16) + m,l (f32)
    __bf16* Ob = (__bf16*)Opart;
#pragma unroll
    for (int r = 0; r < 4; r++) {
      const int slotA = bh * 1536 + (q0 + lg * 4 + r) - 512;
      const int slotB = slotA + 16;
      const size_t baseA = ((size_t)(kind * 49152 + slotA)) * 64;
      const size_t baseB = ((size_t)(kind * 49152 + slotB)) * 64;
#pragma unroll
      for (int dj = 0; dj < 4; dj++) {
        Ob[baseA + dj * 16 + lr] = (__bf16)oA[dj][r];
        Ob[baseB + dj * 16 + lr] = (__bf16)oB[dj][r];
      }
    }
    if (lg == 0) {                       // one writer per row
      const int slA = bh * 1536 + (q0 + lr) - 512;
      Mp[kind * 49152 + slA] = mA;
      Lp[kind * 49152 + slA] = lA;
      Mp[kind * 49152 + slA + 16] = mB;
      Lp[kind * 49152 + slA + 16] = lB;
    }
  }
}

// combine L/R partials: y = (O1*2^(m1-m) + O2*2^(m2-m)) / (l1*2^(m1-m)+l2*2^(m2-m))
__global__ void __launch_bounds__(256) attn_merge(
    const unsigned short* __restrict__ Op, const float* __restrict__ Mp,
    const float* __restrict__ Lp, unsigned short* __restrict__ yatt) {
  const int gid = blockIdx.x * 256 + threadIdx.x;  // 48*256 = 12288 per bh
  const int sl = gid >> 3;                         // 0..1535
  const int d0 = (gid & 7) * 8;
  const int bh = blockIdx.y;
  const int slot = bh * 1536 + sl;
  const float m1 = Mp[slot], m2 = Mp[49152 + slot];
  const float l1 = Lp[slot], l2 = Lp[49152 + slot];
  const float mx = fmaxf(m1, m2);
  const float w1 = exp2f(m1 - mx), w2 = exp2f(m2 - mx);
  const float inv = 1.0f / (l1 * w1 + l2 * w2);
  u16x8 a = *(const u16x8*)(Op + (size_t)slot * 64 + d0);
  u16x8 b = *(const u16x8*)(Op + (size_t)(49152 + slot) * 64 + d0);
  const int qr = 512 + sl;
  unsigned short* dst = yatt +
      ((size_t)((bh >> 4) * 2048 + qr)) * 1024 + (bh & 15) * 64 + d0;
  u16x8 o;
#pragma unroll
  for (int j = 0; j < 8; j++)
    o[j] = f2b((b2f(a[j]) * w1 + b2f(b[j]) * w2) * inv);
  *(u16x8*)dst = o;
}

// ---------------- launcher ----------------

extern "C" void kernel_launch(void* const* d_in, const int* in_sizes, int n_in,
                              void* d_out, int out_size, void* d_ws,
                              size_t ws_size, hipStream_t stream) {
  (void)in_sizes; (void)n_in; (void)out_size; (void)ws_size;
  const float* x      = (const float*)d_in[0];  // [2,2048,1024]
  const float* w_qkv  = (const float*)d_in[1];  // [1024,3072]
  const float* b_qkv  = (const float*)d_in[2];  // [3072]
  const float* w_proj = (const float*)d_in[3];  // [1024,1024]
  const float* b_proj = (const float*)d_in[4];  // [1024]
  float* out = (float*)d_out;                   // [2,2048,1024] f32

  unsigned short* ws     = (unsigned short*)d_ws;
  unsigned short* xb     = ws;                                  // 4096*1024
  unsigned short* wqkvT  = xb     + (size_t)4096 * 1024;        // 3072*1024
  unsigned short* wprojT = wqkvT  + (size_t)3072 * 1024;        // 1024*1024
  unsigned short* Qh     = wprojT + (size_t)1024 * 1024;        // 2*16*2048*64
  unsigned short* Kh     = Qh     + (size_t)2 * 16 * 2048 * 64;
  unsigned short* Vh     = Kh     + (size_t)2 * 16 * 2048 * 64; // [B,H,D,T]
  unsigned short* yatt   = Vh     + (size_t)2 * 16 * 2048 * 64; // 4096*1024

  // attn partials alias xb/wqkvT (dead after QKV GEMM); wprojT untouched.
  unsigned short* Opart = ws;                      // [2][49152][64] bf16
  float* Mp = (float*)(ws + (size_t)6291456);      // [2][49152] f32
  float* Lp = Mp + 2 * 49152;                      // [2][49152] f32

  cvt_f32_to_bf16<<<4096, 256, 0, stream>>>(x, xb, 1048576);
  transpose_f32_to_bf16<<<dim3(96, 32), dim3(32, 8), 0, stream>>>(w_qkv, wqkvT, 1024, 3072);
  transpose_f32_to_bf16<<<dim3(32, 32), dim3(32, 8), 0, stream>>>(w_proj, wprojT, 1024, 1024);

  gemm_bt<0><<<dim3(32, 24), 256, 0, stream>>>(xb, wqkvT, b_qkv, Qh, Kh, Vh,
                                               nullptr, 4096, 3072, 1024);
  attn_kernel<<<896, 256, 0, stream>>>(Qh, Kh, Vh, yatt, Opart, Mp, Lp);
  attn_merge<<<dim3(48, 32), 256, 0, stream>>>(Opart, Mp, Lp, yatt);
  gemm_bt<1><<<dim3(32, 8), 256, 0, stream>>>(yatt, wprojT, b_proj, nullptr,
                                              nullptr, nullptr, out, 4096, 1024, 1024);
}